// Round 2
// baseline (716.765 us; speedup 1.0000x reference)
//
#include <hip/hip_runtime.h>
#include <hip/hip_bf16.h>
#include <hip/hip_cooperative_groups.h>

namespace cg = cooperative_groups;

typedef __attribute__((ext_vector_type(8))) short short8;
typedef __attribute__((ext_vector_type(4))) float floatx4;
typedef __attribute__((ext_vector_type(8))) unsigned short ushortx8;
typedef __attribute__((ext_vector_type(4))) unsigned short ushortx4;
typedef unsigned short u16;

#define HIDDEN 1024
#define NH 16
#define HD 64
#define SEQ 2048
#define CHUNK 128
#define NCHUNK (SEQ / CHUNK)  // 16

__device__ __forceinline__ u16 f2bf(float f) {
    union { float f; unsigned u; } v; v.f = f;
    unsigned r = v.u + 0x7fffu + ((v.u >> 16) & 1u);
    return (u16)(r >> 16);
}
__device__ __forceinline__ float bf2f(u16 u) {
    union { unsigned u; float f; } v; v.u = ((unsigned)u) << 16;
    return v.f;
}

// async 16B global->LDS. LDS dest is wave-uniform base + lane*16 (no pad);
// read-side bank conflicts handled by XOR chunk swizzle on the GLOBAL addr.
__device__ __forceinline__ void gl_lds16(const u16* g, u16* l) {
    __builtin_amdgcn_global_load_lds(
        (const __attribute__((address_space(1))) void*)g,
        (__attribute__((address_space(3))) void*)l,
        16, 0, 0);
}

// ===========================================================================
// MEGA cooperative kernel: all 6 phases in one launch, grid-sync between.
// 256 blocks x 512 threads (1 block/CU, 2 waves/SIMD). LDS 59,648 B shared
// union across phases. All per-phase math is bit-identical to the verified
// standalone kernels (same MFMA chains, same swizzles, same f2bf order).
// ===========================================================================
__global__ __launch_bounds__(512, 2)
void mega(const float* __restrict__ x,  const float* __restrict__ Wq,
          const float* __restrict__ Wk, const float* __restrict__ Wv,
          const float* __restrict__ Wo,
          u16* __restrict__ xb, u16* __restrict__ Wb, u16* __restrict__ Wob,
          u16* __restrict__ qkb, u16* __restrict__ kT_b, u16* __restrict__ vT_b,
          float* __restrict__ S_ws, float* __restrict__ ksum_ws,
          u16* __restrict__ kvpref_b, float* __restrict__ kspref,
          u16* __restrict__ attnb, float* __restrict__ out)
{
    __shared__ __align__(16) u16 smem[29824];  // 59648 B union
    cg::grid_group grid = cg::this_grid();

    const int bid = blockIdx.x;          // 0..255
    const int t = threadIdx.x;           // 0..511
    const int lane = t & 63, w = t >> 6; // 8 waves
    const int ln = lane & 15, q4 = lane >> 4;

    // ---------------- Phase 1: fp32 -> bf16 convert (grid-stride) ----------
    {
        const int total4 = 1572864;  // 6M floats / 4
        for (int idx = bid * 512 + t; idx < total4; idx += 131072) {
            const float4* src; u16* dst; int off;
            if (idx < 524288)       { src = (const float4*)x;  dst = xb;            off = idx; }
            else if (idx < 786432)  { src = (const float4*)Wq; dst = Wb;            off = idx - 524288; }
            else if (idx < 1048576) { src = (const float4*)Wk; dst = Wb + 1048576;  off = idx - 786432; }
            else if (idx < 1310720) { src = (const float4*)Wv; dst = Wb + 2097152;  off = idx - 1048576; }
            else                    { src = (const float4*)Wo; dst = Wob;           off = idx - 1310720; }
            float4 v = src[off];
            ushortx4 u = { f2bf(v.x), f2bf(v.y), f2bf(v.z), f2bf(v.w) };
            *(ushortx4*)(dst + (size_t)off * 4) = u;
        }
    }
    __threadfence(); grid.sync(); __threadfence();

    // ---------------- Phase 2: QKV GEMM, 128x192 tile, 256 tiles -----------
    {
        u16* As = smem;          // [128][64] 8192 u16
        u16* Bs = smem + 8192;   // [192][64] 12288 u16
        const int tx = bid & 15, ty = bid >> 4;
        const int n0 = tx * 192, m0 = ty * 128;
        const int r_in = t >> 3;
        const int csw = (((t & 7) ^ (r_in & 7)) << 3);
        const u16* Ag = xb + (size_t)(m0 + r_in) * 1024 + csw;
        const u16* Bg = Wb + (size_t)(n0 + r_in) * 1024 + csw;
        const int wm = (w >> 2) * 64, wn = (w & 3) * 48;

        floatx4 acc[4][3];
#pragma unroll
        for (int i = 0; i < 4; i++)
#pragma unroll
            for (int j = 0; j < 3; j++) acc[i][j] = (floatx4)0.0f;

        for (int k0 = 0; k0 < 1024; k0 += 64) {
            if (k0) __syncthreads();
            gl_lds16(Ag,          &As[t * 8]);
            gl_lds16(Ag + 65536,  &As[4096 + t * 8]);
            gl_lds16(Bg,          &Bs[t * 8]);
            gl_lds16(Bg + 65536,  &Bs[4096 + t * 8]);
            gl_lds16(Bg + 131072, &Bs[8192 + t * 8]);
            Ag += 64; Bg += 64;
            __syncthreads();
#pragma unroll
            for (int s = 0; s < 2; s++) {
                const int rc = (((s * 4 + q4) ^ (ln & 7)) << 3);
                short8 af[4], bfr[3];
#pragma unroll
                for (int i = 0; i < 4; i++)
                    af[i] = *(const short8*)&As[(wm + i * 16 + ln) * 64 + rc];
#pragma unroll
                for (int j = 0; j < 3; j++)
                    bfr[j] = *(const short8*)&Bs[(wn + j * 16 + ln) * 64 + rc];
#pragma unroll
                for (int i = 0; i < 4; i++)
#pragma unroll
                    for (int j = 0; j < 3; j++)
                        acc[i][j] = __builtin_amdgcn_mfma_f32_16x16x32_bf16(af[i], bfr[j], acc[i][j], 0, 0, 0);
            }
        }
#pragma unroll
        for (int i = 0; i < 4; i++)
#pragma unroll
            for (int j = 0; j < 3; j++) {
                const int mb = m0 + wm + i * 16 + q4 * 4;
                const int n = n0 + wn + j * 16 + ln;
                const int grp = n >> 10;   // uniform per fragment (16-col span)
                const int nh = n & 1023, h2 = nh >> 6, e = nh & 63;
                float vals[4];
#pragma unroll
                for (int r = 0; r < 4; r++) {
                    float v = acc[i][j][r];
                    if (grp < 2) v = (v > 0.f) ? (v + 1.f) : __expf(v);
                    vals[r] = v;
                }
                if (grp == 0) {
#pragma unroll
                    for (int r = 0; r < 4; r++) qkb[(size_t)(mb + r) * 2048 + nh] = f2bf(vals[r]);
                } else if (grp == 1) {
#pragma unroll
                    for (int r = 0; r < 4; r++) qkb[(size_t)(mb + r) * 2048 + 1024 + nh] = f2bf(vals[r]);
                    ushortx4 u = { f2bf(vals[0]), f2bf(vals[1]), f2bf(vals[2]), f2bf(vals[3]) };
                    *(ushortx4*)&kT_b[(size_t)(h2 * 64 + e) * 2048 + mb] = u;
                } else {
                    ushortx4 u = { f2bf(vals[0]), f2bf(vals[1]), f2bf(vals[2]), f2bf(vals[3]) };
                    *(ushortx4*)&vT_b[(size_t)(h2 * 64 + e) * 2048 + mb] = u;
                }
            }
    }
    __threadfence(); grid.sync(); __threadfence();

    // ---------------- Phase 3: chunk stats S_c = K^T V per (c,h) -----------
    {
        u16* kT_l = smem;          // [64][128]
        u16* vT_l = smem + 8192;
        const int c = bid & 15, h = bid >> 4;
#pragma unroll
        for (int rnd = 0; rnd < 2; rnd++) {
            const int s2 = rnd * 512 + t;
            const int d = s2 >> 4, cc = s2 & 15;
            const size_t gsrc = (size_t)(h * 64 + d) * 2048 + c * 128 + ((cc ^ (d & 7)) << 3);
            gl_lds16(kT_b + gsrc, &kT_l[s2 * 8]);
            gl_lds16(vT_b + gsrc, &vT_l[s2 * 8]);
        }
        __syncthreads();
        const int dblk = w & 3, ep = w >> 2;
        floatx4 sacc[2];
#pragma unroll
        for (int jj = 0; jj < 2; jj++) sacc[jj] = (floatx4)0.0f;
#pragma unroll
        for (int ks = 0; ks < 4; ks++) {
            const int rc = (((ks * 4 + q4) ^ (ln & 7)) << 3);
            short8 af = *(const short8*)&kT_l[(dblk * 16 + ln) * 128 + rc];
#pragma unroll
            for (int jj = 0; jj < 2; jj++) {
                short8 bfr = *(const short8*)&vT_l[((ep * 2 + jj) * 16 + ln) * 128 + rc];
                sacc[jj] = __builtin_amdgcn_mfma_f32_16x16x32_bf16(af, bfr, sacc[jj], 0, 0, 0);
            }
        }
        float* Sp = S_ws + ((size_t)(h * NCHUNK + c) << 12);
#pragma unroll
        for (int jj = 0; jj < 2; jj++)
#pragma unroll
            for (int r = 0; r < 4; r++) {
                int d = dblk * 16 + q4 * 4 + r;
                int e = (ep * 2 + jj) * 16 + ln;
                Sp[e * 64 + d] = sacc[jj][r];
            }
        if (t < 64) {  // ksum[d]: swizzle permutes within row; sum invariant
            float s = 0.f;
#pragma unroll
            for (int cc = 0; cc < 16; cc++) {
                ushortx8 v8 = *(const ushortx8*)&kT_l[t * 128 + cc * 8];
#pragma unroll
                for (int jj = 0; jj < 8; jj++) s += bf2f(v8[jj]);
            }
            ksum_ws[(h * NCHUNK + c) * 64 + t] = s;
        }
    }
    __threadfence(); grid.sync(); __threadfence();

    // ---------------- Phase 4: exclusive chunk-prefix scan -----------------
    {
        if (t < 64) {
            const int g = bid * 64 + t;            // 0..16383 scan lanes
            const int h = g >> 10;
            const int li = (g & 1023) * 4;         // 4 consecutive d's of one e-row
            const int e = li >> 6, d0 = li & 63;
            const int slot = e * 64 + ((((d0 >> 3) ^ (e & 7)) << 3) | (d0 & 7));
            float a0 = 0.f, a1 = 0.f, a2 = 0.f, a3 = 0.f;
            for (int c2 = 0; c2 < 16; c2++) {
                ushortx4 u = { f2bf(a0), f2bf(a1), f2bf(a2), f2bf(a3) };  // exclusive
                *(ushortx4*)&kvpref_b[(((size_t)(h * 16 + c2)) << 12) + slot] = u;
                float4 s4 = *(const float4*)(S_ws + (((size_t)(h * 16 + c2)) << 12) + li);
                a0 += s4.x; a1 += s4.y; a2 += s4.z; a3 += s4.w;
            }
        } else if (t < 128 && bid < 16) {
            const int h = bid, d = t - 64;
            float a = 0.f;
            for (int c2 = 0; c2 < 16; c2++) {
                kspref[(h * 16 + c2) * 64 + d] = a;  // exclusive
                a += ksum_ws[(h * 16 + c2) * 64 + d];
            }
        }
    }
    __threadfence(); grid.sync(); __threadfence();

    // ---------------- Phase 5: attention output per (c,h) ------------------
    {
        u16* q_l   = smem;           // [128][64] swizzled (8192)
        u16* k_l   = smem + 8192;    // [128][64] swizzled (8192)
        u16* kvT_l = smem + 16384;   // [64][64] swizzled (4096)
        u16* vT_l  = smem + 20480;   // [64][128] swizzled (8192)
        u16* P_l   = smem;           // [128][136] (17408) aliases q+k+kv when dead
        float* kpref  = (float*)(smem + 28672);  // [64]
        float* denom4 = kpref + 64;              // [4][128]

        const int c = bid & 15, h = bid >> 4;

        // async staging: q,k rows (swizzled), vT rows (swizzled), kv prefix
        {
            const int row = t >> 3, cc = t & 7;
            const size_t gq = (size_t)(c * CHUNK + row) * 2048 + h * 64
                            + (size_t)((cc ^ (row & 7)) << 3);
            gl_lds16(qkb + gq,        &q_l[t * 8]);
            gl_lds16(qkb + gq + 1024, &k_l[t * 8]);
            const int row2 = row + 64;
            const size_t gq2 = (size_t)(c * CHUNK + row2) * 2048 + h * 64
                             + (size_t)((cc ^ (row2 & 7)) << 3);
            gl_lds16(qkb + gq2,        &q_l[4096 + t * 8]);
            gl_lds16(qkb + gq2 + 1024, &k_l[4096 + t * 8]);
            const int d = t >> 4, cv = t & 15;
            gl_lds16(vT_b + (size_t)(h * 64 + d) * 2048 + c * 128 + ((cv ^ (d & 7)) << 3),
                     &vT_l[t * 8]);
            const int d2 = d + 32;
            gl_lds16(vT_b + (size_t)(h * 64 + d2) * 2048 + c * 128 + ((cv ^ (d2 & 7)) << 3),
                     &vT_l[4096 + t * 8]);
            gl_lds16(kvpref_b + (((size_t)(h * 16 + c)) << 12) + t * 8, &kvT_l[t * 8]);
        }
        if (t < 64) kpref[t] = kspref[(h * 16 + c) * 64 + t];
        __syncthreads();

        // P = QK^T : wave tile 64 rows x 32 cols, K=64
        const int pm = (w >> 2) * 64, pn = (w & 3) * 32;
        floatx4 pacc[4][2];
#pragma unroll
        for (int i = 0; i < 4; i++)
#pragma unroll
            for (int j = 0; j < 2; j++) pacc[i][j] = (floatx4)0.0f;
#pragma unroll
        for (int s = 0; s < 2; s++) {
            const int rc = (((s * 4 + q4) ^ (ln & 7)) << 3);
            short8 af[4], bfr[2];
#pragma unroll
            for (int i = 0; i < 4; i++)
                af[i] = *(const short8*)&q_l[(pm + i * 16 + ln) * 64 + rc];
#pragma unroll
            for (int j = 0; j < 2; j++)
                bfr[j] = *(const short8*)&k_l[(pn + j * 16 + ln) * 64 + rc];
#pragma unroll
            for (int i = 0; i < 4; i++)
#pragma unroll
                for (int j = 0; j < 2; j++)
                    pacc[i][j] = __builtin_amdgcn_mfma_f32_16x16x32_bf16(af[i], bfr[j], pacc[i][j], 0, 0, 0);
        }
        // causal mask + partial rowsum per 32-col group
#pragma unroll
        for (int i = 0; i < 4; i++)
#pragma unroll
            for (int r = 0; r < 4; r++) {
                int rowi = pm + i * 16 + q4 * 4 + r;
                float rs = 0.f;
#pragma unroll
                for (int j = 0; j < 2; j++) {
                    int col = pn + j * 16 + ln;
                    float p = pacc[i][j][r];
                    if (col > rowi) p = 0.f;
                    pacc[i][j][r] = p;
                    rs += p;
                }
#pragma unroll
                for (int off = 1; off < 16; off <<= 1) rs += __shfl_xor(rs, off, 64);
                if (ln == 0) denom4[(w & 3) * 128 + rowi] = rs;
            }
        // O_inter = Q @ KV_prefix : wave rows ob..ob+15
        const int ob = w * 16;
        floatx4 oacc[4];
#pragma unroll
        for (int j = 0; j < 4; j++) oacc[j] = (floatx4)0.0f;
#pragma unroll
        for (int s = 0; s < 2; s++) {
            const int rc = (((s * 4 + q4) ^ (ln & 7)) << 3);
            short8 af = *(const short8*)&q_l[(ob + ln) * 64 + rc];
#pragma unroll
            for (int j = 0; j < 4; j++) {
                short8 bfr = *(const short8*)&kvT_l[(j * 16 + ln) * 64 + rc];
                oacc[j] = __builtin_amdgcn_mfma_f32_16x16x32_bf16(af, bfr, oacc[j], 0, 0, 0);
            }
        }
        __syncthreads();  // denom rowsums visible; q/k/kv MFMA reads done
        // denominator inter: q_i . kpref
        if (t < 128) {
            float s = 0.f;
#pragma unroll
            for (int c8 = 0; c8 < 8; c8++) {
                ushortx8 v8 = *(const ushortx8*)&q_l[t * 64 + ((c8 ^ (t & 7)) << 3)];
#pragma unroll
                for (int jj = 0; jj < 8; jj++) s += bf2f(v8[jj]) * kpref[c8 * 8 + jj];
            }
            denom4[t] += s;
        }
        __syncthreads();  // q_l reads done; safe to overwrite with P
        // write masked P (bf16, unswizzled, pad 136)
#pragma unroll
        for (int i = 0; i < 4; i++)
#pragma unroll
            for (int j = 0; j < 2; j++)
#pragma unroll
                for (int r = 0; r < 4; r++) {
                    int rowi = pm + i * 16 + q4 * 4 + r;
                    int col = pn + j * 16 + ln;
                    P_l[rowi * 136 + col] = f2bf(pacc[i][j][r]);
                }
        __syncthreads();
        // O_intra = P @ V : rows ob..ob+15, causal skip
        for (int ks = 0; ks <= (w >> 1); ks++) {
            short8 af = *(const short8*)&P_l[(ob + ln) * 136 + ks * 32 + q4 * 8];
            const int rc = (((ks * 4 + q4) ^ (ln & 7)) << 3);
#pragma unroll
            for (int j = 0; j < 4; j++) {
                short8 bfr = *(const short8*)&vT_l[(j * 16 + ln) * 128 + rc];
                oacc[j] = __builtin_amdgcn_mfma_f32_16x16x32_bf16(af, bfr, oacc[j], 0, 0, 0);
            }
        }
        // normalize + store
#pragma unroll
        for (int r = 0; r < 4; r++) {
            const int rowi = ob + q4 * 4 + r;
            float den = denom4[rowi] + denom4[128 + rowi] + denom4[256 + rowi] + denom4[384 + rowi];
            den = fmaxf(den, 1e-6f);
#pragma unroll
            for (int j = 0; j < 4; j++) {
                int e = j * 16 + ln;
                attnb[(size_t)(c * CHUNK + rowi) * HIDDEN + h * HD + e] = f2bf(oacc[j][r] / den);
            }
        }
    }
    __threadfence(); grid.sync(); __threadfence();

    // ---------------- Phase 6: out = attn @ Wo^T, 128x64 tile --------------
    {
        u16* As = smem;          // [128][64]
        u16* Bs = smem + 8192;   // [64][64]
        const int m0 = (bid >> 4) * 128, n0 = (bid & 15) * 64;
        const int r_in = t >> 3;
        const int csw = (((t & 7) ^ (r_in & 7)) << 3);
        const u16* Ag = attnb + (size_t)(m0 + r_in) * 1024 + csw;
        const u16* Bg = Wob + (size_t)(n0 + r_in) * 1024 + csw;
        const int wm = (w >> 1) * 32, wn = (w & 1) * 32;

        floatx4 acc[2][2];
#pragma unroll
        for (int i = 0; i < 2; i++)
#pragma unroll
            for (int j = 0; j < 2; j++) acc[i][j] = (floatx4)0.0f;

        for (int k0 = 0; k0 < 1024; k0 += 64) {
            if (k0) __syncthreads();
            gl_lds16(Ag,         &As[t * 8]);
            gl_lds16(Ag + 65536, &As[4096 + t * 8]);
            gl_lds16(Bg,         &Bs[t * 8]);
            Ag += 64; Bg += 64;
            __syncthreads();
#pragma unroll
            for (int s = 0; s < 2; s++) {
                const int rc = (((s * 4 + q4) ^ (ln & 7)) << 3);
                short8 af[2], bfr[2];
#pragma unroll
                for (int i = 0; i < 2; i++)
                    af[i] = *(const short8*)&As[(wm + i * 16 + ln) * 64 + rc];
#pragma unroll
                for (int j = 0; j < 2; j++)
                    bfr[j] = *(const short8*)&Bs[(wn + j * 16 + ln) * 64 + rc];
#pragma unroll
                for (int i = 0; i < 2; i++)
#pragma unroll
                    for (int j = 0; j < 2; j++)
                        acc[i][j] = __builtin_amdgcn_mfma_f32_16x16x32_bf16(af[i], bfr[j], acc[i][j], 0, 0, 0);
            }
        }
#pragma unroll
        for (int i = 0; i < 2; i++)
#pragma unroll
            for (int j = 0; j < 2; j++)
#pragma unroll
                for (int r = 0; r < 4; r++) {
                    int m = m0 + wm + i * 16 + q4 * 4 + r;
                    int n = n0 + wn + j * 16 + ln;
                    out[(size_t)m * 1024 + n] = acc[i][j][r];
                }
    }
}

// ===========================================================================
// Fallback path: the verified round-1 six-kernel pipeline (used only if the
// cooperative launch is rejected by the runtime).
// ===========================================================================
__global__ __launch_bounds__(256)
void convert_all(const float* __restrict__ x,  const float* __restrict__ Wq,
                 const float* __restrict__ Wk, const float* __restrict__ Wv,
                 const float* __restrict__ Wo,
                 u16* __restrict__ xb, u16* __restrict__ Wb, u16* __restrict__ Wob)
{
    const int total4 = 1572864;
    for (int idx = blockIdx.x * 256 + threadIdx.x; idx < total4; idx += gridDim.x * 256) {
        const float4* src; u16* dst; int off;
        if (idx < 524288)       { src = (const float4*)x;  dst = xb;            off = idx; }
        else if (idx < 786432)  { src = (const float4*)Wq; dst = Wb;            off = idx - 524288; }
        else if (idx < 1048576) { src = (const float4*)Wk; dst = Wb + 1048576;  off = idx - 786432; }
        else if (idx < 1310720) { src = (const float4*)Wv; dst = Wb + 2097152;  off = idx - 1048576; }
        else                    { src = (const float4*)Wo; dst = Wob;           off = idx - 1310720; }
        float4 v = src[off];
        ushortx4 u = { f2bf(v.x), f2bf(v.y), f2bf(v.z), f2bf(v.w) };
        *(ushortx4*)(dst + (size_t)off * 4) = u;
    }
}

__global__ __launch_bounds__(256, 3)
void qkv_gemm64(const u16* __restrict__ A, const u16* __restrict__ Bm,
                u16* __restrict__ qkb, u16* __restrict__ kT_b, u16* __restrict__ vT_b)
{
    __shared__ u16 As[64 * 64];
    __shared__ u16 Bs[128 * 64];
    const int n0 = blockIdx.x * 128, m0 = blockIdx.y * 64;
    const int t = threadIdx.x;
    const int lane = t & 63, wave = t >> 6;
    const int ln = lane & 15, q4 = lane >> 4;
    const int wm = (wave >> 1) * 32, wn = (wave & 1) * 64;
    const int r_in = t >> 3;
    const int csw = (((t & 7) ^ (r_in & 7)) << 3);
    const u16* Ag = A + (size_t)(m0 + r_in) * 1024 + csw;
    const u16* Bg = Bm + (size_t)(n0 + r_in) * 1024 + csw;
    floatx4 acc[2][4];
#pragma unroll
    for (int i = 0; i < 2; i++)
#pragma unroll
        for (int j = 0; j < 4; j++) acc[i][j] = (floatx4)0.0f;
    for (int k0 = 0; k0 < 1024; k0 += 64) {
        if (k0) __syncthreads();
        gl_lds16(Ag, &As[t * 8]);
        gl_lds16(Ag + 32 * 1024, &As[2048 + t * 8]);
#pragma unroll
        for (int i = 0; i < 4; i++)
            gl_lds16(Bg + (size_t)i * 32 * 1024, &Bs[i * 2048 + t * 8]);
        Ag += 64; Bg += 64;
        __syncthreads();
#pragma unroll
        for (int s = 0; s < 2; s++) {
            const int rc = (((s * 4 + q4) ^ (ln & 7)) << 3);
            short8 af[2], bfr[4];
#pragma unroll
            for (int i = 0; i < 2; i++)
                af[i] = *(const short8*)&As[(wm + i * 16 + ln) * 64 + rc];
#pragma unroll
            for (int j = 0; j < 4; j++)
                bfr[j] = *(const short8*)&Bs[(wn + j * 16 + ln) * 64 + rc];
#pragma unroll
            for (int i = 0; i < 2; i++)
#pragma unroll
                for (int j = 0; j < 4; j++)
                    acc[i][j] = __builtin_amdgcn_mfma_f32_16x16x32_bf16(af[i], bfr[j], acc[i][j], 0, 0, 0);
        }
    }
    const int grp = n0 >> 10;
#pragma unroll
    for (int i = 0; i < 2; i++)
#pragma unroll
        for (int j = 0; j < 4; j++) {
            const int mb = m0 + wm + i * 16 + q4 * 4;
            const int n = n0 + wn + j * 16 + ln;
            const int nh = n & 1023, h = nh >> 6, e = nh & 63;
            float vals[4];
#pragma unroll
            for (int r = 0; r < 4; r++) {
                float v = acc[i][j][r];
                if (grp < 2) v = (v > 0.f) ? (v + 1.f) : __expf(v);
                vals[r] = v;
            }
            if (grp == 0) {
#pragma unroll
                for (int r = 0; r < 4; r++) qkb[(size_t)(mb + r) * 2048 + nh] = f2bf(vals[r]);
            } else if (grp == 1) {
#pragma unroll
                for (int r = 0; r < 4; r++) qkb[(size_t)(mb + r) * 2048 + 1024 + nh] = f2bf(vals[r]);
                ushortx4 u = { f2bf(vals[0]), f2bf(vals[1]), f2bf(vals[2]), f2bf(vals[3]) };
                *(ushortx4*)&kT_b[(size_t)(h * 64 + e) * 2048 + mb] = u;
            } else {
                ushortx4 u = { f2bf(vals[0]), f2bf(vals[1]), f2bf(vals[2]), f2bf(vals[3]) };
                *(ushortx4*)&vT_b[(size_t)(h * 64 + e) * 2048 + mb] = u;
            }
        }
}

__global__ __launch_bounds__(256, 2)
void chunk_stats2(const u16* __restrict__ kT_b, const u16* __restrict__ vT_b,
                  float* __restrict__ S_ws, float* __restrict__ ksum_ws)
{
    __shared__ u16 kT_l[64 * 128];
    __shared__ u16 vT_l[64 * 128];
    const int c = blockIdx.x, h = blockIdx.y;
    const int t = threadIdx.x;
    const int lane = t & 63, w = t >> 6;
    const int ln = lane & 15, q4 = lane >> 4;
#pragma unroll
    for (int i = 0; i < 4; i++) {
        const int d0 = w * 16 + i * 4 + (lane >> 4);
        const int cc = lane & 15;
        const size_t gsrc = (size_t)(h * 64 + d0) * 2048 + c * 128 + ((cc ^ (d0 & 7)) << 3);
        gl_lds16(kT_b + gsrc, &kT_l[(w * 16 + i * 4) * 128 + lane * 8]);
        gl_lds16(vT_b + gsrc, &vT_l[(w * 16 + i * 4) * 128 + lane * 8]);
    }
    __syncthreads();
    floatx4 sacc[4];
#pragma unroll
    for (int j = 0; j < 4; j++) sacc[j] = (floatx4)0.0f;
#pragma unroll
    for (int ks = 0; ks < 4; ks++) {
        const int rc = (((ks * 4 + q4) ^ (ln & 7)) << 3);
        short8 af = *(const short8*)&kT_l[(w * 16 + ln) * 128 + rc];
#pragma unroll
        for (int j = 0; j < 4; j++) {
            short8 bfr = *(const short8*)&vT_l[(j * 16 + ln) * 128 + rc];
            sacc[j] = __builtin_amdgcn_mfma_f32_16x16x32_bf16(af, bfr, sacc[j], 0, 0, 0);
        }
    }
    float* Sp = S_ws + ((size_t)(h * NCHUNK + c) << 12);
#pragma unroll
    for (int j = 0; j < 4; j++)
#pragma unroll
        for (int r = 0; r < 4; r++) {
            int d = w * 16 + q4 * 4 + r;
            int e = j * 16 + ln;
            Sp[e * 64 + d] = sacc[j][r];
        }
    if (t < 64) {
        float s = 0.f;
#pragma unroll
        for (int cc = 0; cc < 16; cc++) {
            ushortx8 v8 = *(const ushortx8*)&kT_l[t * 128 + cc * 8];
#pragma unroll
            for (int jj = 0; jj < 8; jj++) s += bf2f(v8[jj]);
        }
        ksum_ws[(h * NCHUNK + c) * 64 + t] = s;
    }
}

__global__ __launch_bounds__(256)
void scan_kv(const float* __restrict__ S_ws, const float* __restrict__ ksum_ws,
             u16* __restrict__ kvpref_b, float* __restrict__ kspref)
{
    const int h = blockIdx.x, qt = blockIdx.y;
    const int t = threadIdx.x;
    const int li = qt * 1024 + t * 4;
    const int e = li >> 6, d0 = li & 63;
    const int slot = e * 64 + ((((d0 >> 3) ^ (e & 7)) << 3) | (d0 & 7));
    float a0 = 0.f, a1 = 0.f, a2 = 0.f, a3 = 0.f;
    for (int c = 0; c < 16; c++) {
        ushortx4 u = { f2bf(a0), f2bf(a1), f2bf(a2), f2bf(a3) };
        *(ushortx4*)&kvpref_b[(((size_t)(h * 16 + c)) << 12) + slot] = u;
        float4 s4 = *(const float4*)(S_ws + (((size_t)(h * 16 + c)) << 12) + li);
        a0 += s4.x; a1 += s4.y; a2 += s4.z; a3 += s4.w;
    }
    if (qt == 0 && t < 64) {
        float a = 0.f;
        for (int c = 0; c < 16; c++) {
            kspref[(h * 16 + c) * 64 + t] = a;
            a += ksum_ws[(h * 16 + c) * 64 + t];
        }
    }
}

__global__ __launch_bounds__(512, 2)
void attn_out2(const u16* __restrict__ qkb, const u16* __restrict__ vT_b,
               const u16* __restrict__ kvpref_b, const float* __restrict__ kspref,
               u16* __restrict__ attnb)
{
    __shared__ __align__(16) u16 smem[29824];
    u16* q_l   = smem;
    u16* k_l   = smem + 8192;
    u16* kvT_l = smem + 16384;
    u16* vT_l  = smem + 20480;
    u16* P_l   = smem;
    float* kpref  = (float*)(smem + 28672);
    float* denom4 = kpref + 64;

    const int c = blockIdx.x, h = blockIdx.y;
    const int t = threadIdx.x;
    const int lane = t & 63, w = t >> 6;
    const int ln = lane & 15, q4 = lane >> 4;
    {
        const int row = t >> 3, cc = t & 7;
        const size_t gq = (size_t)(c * CHUNK + row) * 2048 + h * 64
                        + (size_t)((cc ^ (row & 7)) << 3);
        gl_lds16(qkb + gq,        &q_l[t * 8]);
        gl_lds16(qkb + gq + 1024, &k_l[t * 8]);
        const int row2 = row + 64;
        const size_t gq2 = (size_t)(c * CHUNK + row2) * 2048 + h * 64
                         + (size_t)((cc ^ (row2 & 7)) << 3);
        gl_lds16(qkb + gq2,        &q_l[4096 + t * 8]);
        gl_lds16(qkb + gq2 + 1024, &k_l[4096 + t * 8]);
        const int d = t >> 4, cv = t & 15;
        gl_lds16(vT_b + (size_t)(h * 64 + d) * 2048 + c * 128 + ((cv ^ (d & 7)) << 3),
                 &vT_l[t * 8]);
        const int d2 = d + 32;
        gl_lds16(vT_b + (size_t)(h * 64 + d2) * 2048 + c * 128 + ((cv ^ (d2 & 7)) << 3),
                 &vT_l[4096 + t * 8]);
        gl_lds16(kvpref_b + (((size_t)(h * 16 + c)) << 12) + t * 8, &kvT_l[t * 8]);
    }
    if (t < 64) kpref[t] = kspref[(h * 16 + c) * 64 + t];
    __syncthreads();
    const int pm = (w >> 2) * 64, pn = (w & 3) * 32;
    floatx4 pacc[4][2];
#pragma unroll
    for (int i = 0; i < 4; i++)
#pragma unroll
        for (int j = 0; j < 2; j++) pacc[i][j] = (floatx4)0.0f;
#pragma unroll
    for (int s = 0; s < 2; s++) {
        const int rc = (((s * 4 + q4) ^ (ln & 7)) << 3);
        short8 af[4], bfr[2];
#pragma unroll
        for (int i = 0; i < 4; i++)
            af[i] = *(const short8*)&q_l[(pm + i * 16 + ln) * 64 + rc];
#pragma unroll
        for (int j = 0; j < 2; j++)
            bfr[j] = *(const short8*)&k_l[(pn + j * 16 + ln) * 64 + rc];
#pragma unroll
        for (int i = 0; i < 4; i++)
#pragma unroll
            for (int j = 0; j < 2; j++)
                pacc[i][j] = __builtin_amdgcn_mfma_f32_16x16x32_bf16(af[i], bfr[j], pacc[i][j], 0, 0, 0);
    }
#pragma unroll
    for (int i = 0; i < 4; i++)
#pragma unroll
        for (int r = 0; r < 4; r++) {
            int rowi = pm + i * 16 + q4 * 4 + r;
            float rs = 0.f;
#pragma unroll
            for (int j = 0; j < 2; j++) {
                int col = pn + j * 16 + ln;
                float p = pacc[i][j][r];
                if (col > rowi) p = 0.f;
                pacc[i][j][r] = p;
                rs += p;
            }
#pragma unroll
            for (int off = 1; off < 16; off <<= 1) rs += __shfl_xor(rs, off, 64);
            if (ln == 0) denom4[(w & 3) * 128 + rowi] = rs;
        }
    const int ob = w * 16;
    floatx4 oacc[4];
#pragma unroll
    for (int j = 0; j < 4; j++) oacc[j] = (floatx4)0.0f;
#pragma unroll
    for (int s = 0; s < 2; s++) {
        const int rc = (((s * 4 + q4) ^ (ln & 7)) << 3);
        short8 af = *(const short8*)&q_l[(ob + ln) * 64 + rc];
#pragma unroll
        for (int j = 0; j < 4; j++) {
            short8 bfr = *(const short8*)&kvT_l[(j * 16 + ln) * 64 + rc];
            oacc[j] = __builtin_amdgcn_mfma_f32_16x16x32_bf16(af, bfr, oacc[j], 0, 0, 0);
        }
    }
    __syncthreads();
    if (t < 128) {
        float s = 0.f;
#pragma unroll
        for (int c8 = 0; c8 < 8; c8++) {
            ushortx8 v8 = *(const ushortx8*)&q_l[t * 64 + ((c8 ^ (t & 7)) << 3)];
#pragma unroll
            for (int jj = 0; jj < 8; jj++) s += bf2f(v8[jj]) * kpref[c8 * 8 + jj];
        }
        denom4[t] += s;
    }
    __syncthreads();
#pragma unroll
    for (int i = 0; i < 4; i++)
#pragma unroll
        for (int j = 0; j < 2; j++)
#pragma unroll
            for (int r = 0; r < 4; r++) {
                int rowi = pm + i * 16 + q4 * 4 + r;
                int col = pn + j * 16 + ln;
                P_l[rowi * 136 + col] = f2bf(pacc[i][j][r]);
            }
    __syncthreads();
    for (int ks = 0; ks <= (w >> 1); ks++) {
        short8 af = *(const short8*)&P_l[(ob + ln) * 136 + ks * 32 + q4 * 8];
        const int rc = (((ks * 4 + q4) ^ (ln & 7)) << 3);
#pragma unroll
        for (int j = 0; j < 4; j++) {
            short8 bfr = *(const short8*)&vT_l[(j * 16 + ln) * 128 + rc];
            oacc[j] = __builtin_amdgcn_mfma_f32_16x16x32_bf16(af, bfr, oacc[j], 0, 0, 0);
        }
    }
#pragma unroll
    for (int r = 0; r < 4; r++) {
        const int rowi = ob + q4 * 4 + r;
        float den = denom4[rowi] + denom4[128 + rowi] + denom4[256 + rowi] + denom4[384 + rowi];
        den = fmaxf(den, 1e-6f);
#pragma unroll
        for (int j = 0; j < 4; j++) {
            int e = j * 16 + ln;
            attnb[(size_t)(c * CHUNK + rowi) * HIDDEN + h * HD + e] = f2bf(oacc[j][r] / den);
        }
    }
}

__global__ __launch_bounds__(256, 3)
void out_gemm64(const u16* __restrict__ A, const u16* __restrict__ Bm,
                float* __restrict__ out)
{
    __shared__ u16 As[64 * 64];
    __shared__ u16 Bs[64 * 64];
    const int n0 = blockIdx.x * 64, m0 = blockIdx.y * 64;
    const int t = threadIdx.x;
    const int lane = t & 63, wave = t >> 6;
    const int ln = lane & 15, q4 = lane >> 4;
    const int wm = (wave >> 1) * 32, wn = (wave & 1) * 32;
    const int r_in = t >> 3;
    const int csw = (((t & 7) ^ (r_in & 7)) << 3);
    const u16* Ag = A + (size_t)(m0 + r_in) * 1024 + csw;
    const u16* Bg = Bm + (size_t)(n0 + r_in) * 1024 + csw;
    floatx4 acc[2][2];
#pragma unroll
    for (int i = 0; i < 2; i++)
#pragma unroll
        for (int j = 0; j < 2; j++) acc[i][j] = (floatx4)0.0f;
    for (int k0 = 0; k0 < 1024; k0 += 64) {
        if (k0) __syncthreads();
        gl_lds16(Ag, &As[t * 8]);
        gl_lds16(Ag + 32 * 1024, &As[2048 + t * 8]);
        gl_lds16(Bg, &Bs[t * 8]);
        gl_lds16(Bg + 32 * 1024, &Bs[2048 + t * 8]);
        Ag += 64; Bg += 64;
        __syncthreads();
#pragma unroll
        for (int s = 0; s < 2; s++) {
            const int rc = (((s * 4 + q4) ^ (ln & 7)) << 3);
            short8 af[2], bfr[2];
#pragma unroll
            for (int i = 0; i < 2; i++)
                af[i] = *(const short8*)&As[(wm + i * 16 + ln) * 64 + rc];
#pragma unroll
            for (int j = 0; j < 2; j++)
                bfr[j] = *(const short8*)&Bs[(wn + j * 16 + ln) * 64 + rc];
#pragma unroll
            for (int i = 0; i < 2; i++)
#pragma unroll
                for (int j = 0; j < 2; j++)
                    acc[i][j] = __builtin_amdgcn_mfma_f32_16x16x32_bf16(af[i], bfr[j], acc[i][j], 0, 0, 0);
        }
    }
#pragma unroll
    for (int i = 0; i < 2; i++)
#pragma unroll
        for (int j = 0; j < 2; j++)
#pragma unroll
            for (int r = 0; r < 4; r++) {
                int m = m0 + wm + i * 16 + q4 * 4 + r;
                int n = n0 + wn + j * 16 + ln;
                out[(size_t)m * 1024 + n] = acc[i][j][r];
            }
}

// ---------------------------------------------------------------------------
// Workspace layout (40 MB used, no aliasing):
//   xb     @  0 MB   4 MB   Wb @ 4 MB 6 MB   Wob @ 10 MB 2 MB
//   qkb    @ 12 MB   8 MB   kT_b @ 20 MB 4 MB   vT_b @ 24 MB 4 MB
//   S_ws   @ 28 MB   4 MB   ksum @ 32 MB 256 KB  attnb @ 33 MB 4 MB
//   kvpref @ 37 MB   2 MB   kspref @ 39 MB 64 KB
// ---------------------------------------------------------------------------
extern "C" void kernel_launch(void* const* d_in, const int* in_sizes, int n_in,
                              void* d_out, int out_size, void* d_ws, size_t ws_size,
                              hipStream_t stream)
{
    const float* x  = (const float*)d_in[0];
    const float* Wq = (const float*)d_in[1];
    const float* Wk = (const float*)d_in[2];
    const float* Wv = (const float*)d_in[3];
    const float* Wo = (const float*)d_in[4];
    float* out = (float*)d_out;

    char* ws = (char*)d_ws;
    const size_t MB = 1024 * 1024;
    u16* xb    = (u16*)(ws);
    u16* Wb    = (u16*)(ws + 4 * MB);
    u16* Wob   = (u16*)(ws + 10 * MB);
    u16* qkb   = (u16*)(ws + 12 * MB);
    u16* kT_b  = (u16*)(ws + 20 * MB);
    u16* vT_b  = (u16*)(ws + 24 * MB);
    float* S_ws    = (float*)(ws + 28 * MB);
    float* ksum_ws = (float*)(ws + 32 * MB);
    u16* attnb = (u16*)(ws + 33 * MB);
    u16* kvpref_b = (u16*)(ws + 37 * MB);
    float* kspref = (float*)(ws + 39 * MB);

    void* args[] = { (void*)&x, (void*)&Wq, (void*)&Wk, (void*)&Wv, (void*)&Wo,
                     (void*)&xb, (void*)&Wb, (void*)&Wob,
                     (void*)&qkb, (void*)&kT_b, (void*)&vT_b,
                     (void*)&S_ws, (void*)&ksum_ws,
                     (void*)&kvpref_b, (void*)&kspref,
                     (void*)&attnb, (void*)&out };
    hipError_t err = hipLaunchCooperativeKernel((void*)mega, dim3(256), dim3(512),
                                                args, 0, stream);
    if (err != hipSuccess) {
        (void)hipGetLastError();  // clear; run verified 6-kernel fallback
        convert_all<<<2048, 256, 0, stream>>>(x, Wq, Wk, Wv, Wo, xb, Wb, Wob);
        qkv_gemm64<<<dim3(24, 32), 256, 0, stream>>>(xb, Wb, qkb, kT_b, vT_b);
        chunk_stats2<<<dim3(NCHUNK, NH), 256, 0, stream>>>(kT_b, vT_b, S_ws, ksum_ws);
        scan_kv<<<dim3(NH, 4), 256, 0, stream>>>(S_ws, ksum_ws, kvpref_b, kspref);
        attn_out2<<<dim3(NCHUNK, NH), 512, 0, stream>>>(qkb, vT_b, kvpref_b, kspref, attnb);
        out_gemm64<<<dim3(16, 32), 256, 0, stream>>>(attnb, Wob, out);
    }
}

// Round 3
// 129.456 us; speedup vs baseline: 5.5367x; 5.5367x over previous
//
#include <hip/hip_runtime.h>
#include <hip/hip_bf16.h>

typedef __attribute__((ext_vector_type(8))) short short8;
typedef __attribute__((ext_vector_type(4))) float floatx4;
typedef __attribute__((ext_vector_type(8))) unsigned short ushortx8;
typedef __attribute__((ext_vector_type(4))) unsigned short ushortx4;
typedef unsigned short u16;

#define HIDDEN 1024
#define NH 16
#define HD 64
#define SEQ 2048
#define CHUNK 128
#define NCHUNK (SEQ / CHUNK)  // 16

__device__ __forceinline__ u16 f2bf(float f) {
    union { float f; unsigned u; } v; v.f = f;
    unsigned r = v.u + 0x7fffu + ((v.u >> 16) & 1u);
    return (u16)(r >> 16);
}
__device__ __forceinline__ float bf2f(u16 u) {
    union { unsigned u; float f; } v; v.u = ((unsigned)u) << 16;
    return v.f;
}

// async 16B global->LDS. LDS dest is wave-uniform base + lane*16 (no pad);
// read-side bank conflicts handled by XOR chunk swizzle on the GLOBAL addr.
__device__ __forceinline__ void gl_lds16(const u16* g, u16* l) {
    __builtin_amdgcn_global_load_lds(
        (const __attribute__((address_space(1))) void*)g,
        (__attribute__((address_space(3))) void*)l,
        16, 0, 0);
}

// ---------------------------------------------------------------------------
// Kernel 0: fp32 -> bf16 of x, Wq|Wk|Wv (fused rows), Wo. ~36 MB traffic.
// ---------------------------------------------------------------------------
__global__ __launch_bounds__(256)
void convert_all(const float* __restrict__ x,  const float* __restrict__ Wq,
                 const float* __restrict__ Wk, const float* __restrict__ Wv,
                 const float* __restrict__ Wo,
                 u16* __restrict__ xb, u16* __restrict__ Wb, u16* __restrict__ Wob)
{
    const int total4 = 1572864;  // 6M floats / 4
    for (int idx = blockIdx.x * 256 + threadIdx.x; idx < total4; idx += gridDim.x * 256) {
        const float4* src; u16* dst; int off;
        if (idx < 524288)       { src = (const float4*)x;  dst = xb;            off = idx; }
        else if (idx < 786432)  { src = (const float4*)Wq; dst = Wb;            off = idx - 524288; }
        else if (idx < 1048576) { src = (const float4*)Wk; dst = Wb + 1048576;  off = idx - 786432; }
        else if (idx < 1310720) { src = (const float4*)Wv; dst = Wb + 2097152;  off = idx - 1048576; }
        else                    { src = (const float4*)Wo; dst = Wob;           off = idx - 1310720; }
        float4 v = src[off];
        ushortx4 u = { f2bf(v.x), f2bf(v.y), f2bf(v.z), f2bf(v.w) };
        *(ushortx4*)(dst + (size_t)off * 4) = u;
    }
}

// ---------------------------------------------------------------------------
// Kernel 1: fused QKV GEMM, 128x128 tile (384 blocks), BK=64, m97-structure:
// global_load_lds 16B staging + XOR swizzle, acc[4][4]/wave (32 MFMA per
// wave-K-step, 65 FLOP per staged byte vs 43 at 64x128). Epilogue:
//   q (cols 0..1023):    elu+1, row-major into qkb[:, 0:1024]
//   k (cols 1024..2047): elu+1, row-major into qkb[:, 1024:2048] AND kT_b[h][d][l]
//   v (cols 2048..3071): vT_b[h][e][l] ONLY
// Per-output MFMA chain identical to round-1 (bitwise same results).
// ---------------------------------------------------------------------------
__global__ __launch_bounds__(256, 3)
void qkv_gemm128(const u16* __restrict__ A, const u16* __restrict__ Bm,
                 u16* __restrict__ qkb, u16* __restrict__ kT_b, u16* __restrict__ vT_b)
{
    __shared__ u16 As[128 * 64];
    __shared__ u16 Bs[128 * 64];
    const int n0 = blockIdx.x * 128, m0 = blockIdx.y * 128;
    const int t = threadIdx.x;
    const int lane = t & 63, wave = t >> 6;
    const int ln = lane & 15, q4 = lane >> 4;
    const int wm = (wave >> 1) * 64, wn = (wave & 1) * 64;
    const int r_in = t >> 3;
    const int csw = (((t & 7) ^ (r_in & 7)) << 3);

    const u16* Ag = A + (size_t)(m0 + r_in) * 1024 + csw;
    const u16* Bg = Bm + (size_t)(n0 + r_in) * 1024 + csw;

    floatx4 acc[4][4];
#pragma unroll
    for (int i = 0; i < 4; i++)
#pragma unroll
        for (int j = 0; j < 4; j++) acc[i][j] = (floatx4)0.0f;

    for (int k0 = 0; k0 < 1024; k0 += 64) {
        if (k0) __syncthreads();
#pragma unroll
        for (int i = 0; i < 4; i++) {
            gl_lds16(Ag + (size_t)i * 32 * 1024, &As[i * 2048 + t * 8]);
            gl_lds16(Bg + (size_t)i * 32 * 1024, &Bs[i * 2048 + t * 8]);
        }
        Ag += 64; Bg += 64;
        __syncthreads();
#pragma unroll
        for (int s = 0; s < 2; s++) {
            const int rc = (((s * 4 + q4) ^ (ln & 7)) << 3);
            short8 af[4], bfr[4];
#pragma unroll
            for (int i = 0; i < 4; i++)
                af[i] = *(const short8*)&As[(wm + i * 16 + ln) * 64 + rc];
#pragma unroll
            for (int j = 0; j < 4; j++)
                bfr[j] = *(const short8*)&Bs[(wn + j * 16 + ln) * 64 + rc];
#pragma unroll
            for (int i = 0; i < 4; i++)
#pragma unroll
                for (int j = 0; j < 4; j++)
                    acc[i][j] = __builtin_amdgcn_mfma_f32_16x16x32_bf16(af[i], bfr[j], acc[i][j], 0, 0, 0);
        }
    }
    const int grp = n0 >> 10;  // 0=q 1=k 2=v (block-uniform: 1024%128==0)
#pragma unroll
    for (int i = 0; i < 4; i++)
#pragma unroll
        for (int j = 0; j < 4; j++) {
            const int mb = m0 + wm + i * 16 + q4 * 4;
            const int n = n0 + wn + j * 16 + ln;
            const int nh = n & 1023, h = nh >> 6, e = nh & 63;
            float vals[4];
#pragma unroll
            for (int r = 0; r < 4; r++) {
                float v = acc[i][j][r];
                if (grp < 2) v = (v > 0.f) ? (v + 1.f) : __expf(v);
                vals[r] = v;
            }
            if (grp == 0) {
#pragma unroll
                for (int r = 0; r < 4; r++) qkb[(size_t)(mb + r) * 2048 + nh] = f2bf(vals[r]);
            } else if (grp == 1) {
#pragma unroll
                for (int r = 0; r < 4; r++) qkb[(size_t)(mb + r) * 2048 + 1024 + nh] = f2bf(vals[r]);
                ushortx4 u = { f2bf(vals[0]), f2bf(vals[1]), f2bf(vals[2]), f2bf(vals[3]) };
                *(ushortx4*)&kT_b[(size_t)(h * 64 + e) * 2048 + mb] = u;
            } else {
                ushortx4 u = { f2bf(vals[0]), f2bf(vals[1]), f2bf(vals[2]), f2bf(vals[3]) };
                *(ushortx4*)&vT_b[(size_t)(h * 64 + e) * 2048 + mb] = u;
            }
        }
}

// ---------------------------------------------------------------------------
// Kernel 2: S_c[d][e] = sum_l K[l][d] V[l][e] per (c,h) via MFMA, staged
// entirely with global_load_lds from kT_b/vT_b (reduction axis l contig).
// Stores S^T [e][d] + ksum[d]. grid (16,16).
// ---------------------------------------------------------------------------
__global__ __launch_bounds__(256, 2)
void chunk_stats2(const u16* __restrict__ kT_b, const u16* __restrict__ vT_b,
                  float* __restrict__ S_ws, float* __restrict__ ksum_ws)
{
    __shared__ u16 kT_l[64 * 128];
    __shared__ u16 vT_l[64 * 128];
    const int c = blockIdx.x, h = blockIdx.y;
    const int t = threadIdx.x;
    const int lane = t & 63, w = t >> 6;
    const int ln = lane & 15, q4 = lane >> 4;
#pragma unroll
    for (int i = 0; i < 4; i++) {
        const int d0 = w * 16 + i * 4 + (lane >> 4);
        const int cc = lane & 15;
        const size_t gsrc = (size_t)(h * 64 + d0) * 2048 + c * 128 + ((cc ^ (d0 & 7)) << 3);
        gl_lds16(kT_b + gsrc, &kT_l[(w * 16 + i * 4) * 128 + lane * 8]);
        gl_lds16(vT_b + gsrc, &vT_l[(w * 16 + i * 4) * 128 + lane * 8]);
    }
    __syncthreads();
    floatx4 sacc[4];
#pragma unroll
    for (int j = 0; j < 4; j++) sacc[j] = (floatx4)0.0f;
#pragma unroll
    for (int ks = 0; ks < 4; ks++) {
        const int rc = (((ks * 4 + q4) ^ (ln & 7)) << 3);
        short8 af = *(const short8*)&kT_l[(w * 16 + ln) * 128 + rc];
#pragma unroll
        for (int j = 0; j < 4; j++) {
            short8 bfr = *(const short8*)&vT_l[(j * 16 + ln) * 128 + rc];
            sacc[j] = __builtin_amdgcn_mfma_f32_16x16x32_bf16(af, bfr, sacc[j], 0, 0, 0);
        }
    }
    float* Sp = S_ws + ((size_t)(h * NCHUNK + c) << 12);
#pragma unroll
    for (int j = 0; j < 4; j++)
#pragma unroll
        for (int r = 0; r < 4; r++) {
            int d = w * 16 + q4 * 4 + r;
            int e = j * 16 + ln;
            Sp[e * 64 + d] = sacc[j][r];  // S^T [e][d]
        }
    if (t < 64) {  // ksum[d]: row-sum of kT_l (swizzle permutes within row; sum invariant)
        float s = 0.f;
#pragma unroll
        for (int cc = 0; cc < 16; cc++) {
            ushortx8 v8 = *(const ushortx8*)&kT_l[t * 128 + cc * 8];
#pragma unroll
            for (int jj = 0; jj < 8; jj++) s += bf2f(v8[jj]);
        }
        ksum_ws[(h * NCHUNK + c) * 64 + t] = s;
    }
}

// ---------------------------------------------------------------------------
// Kernel 2b: exclusive chunk-prefix scan of S (fp32 accumulate) -> kvpref_b
// bf16 PRE-SWIZZLED, + exclusive ksum prefix. grid (NH, 4).
// ---------------------------------------------------------------------------
__global__ __launch_bounds__(256)
void scan_kv(const float* __restrict__ S_ws, const float* __restrict__ ksum_ws,
             u16* __restrict__ kvpref_b, float* __restrict__ kspref)
{
    const int h = blockIdx.x, qt = blockIdx.y;
    const int t = threadIdx.x;
    const int li = qt * 1024 + t * 4;          // linear elem in S^T [e][d]
    const int e = li >> 6, d0 = li & 63;       // 4 consecutive d's, one row
    const int slot = e * 64 + ((((d0 >> 3) ^ (e & 7)) << 3) | (d0 & 7));
    float a0 = 0.f, a1 = 0.f, a2 = 0.f, a3 = 0.f;
    for (int c = 0; c < 16; c++) {
        ushortx4 u = { f2bf(a0), f2bf(a1), f2bf(a2), f2bf(a3) };  // exclusive
        *(ushortx4*)&kvpref_b[(((size_t)(h * 16 + c)) << 12) + slot] = u;
        float4 s4 = *(const float4*)(S_ws + (((size_t)(h * 16 + c)) << 12) + li);
        a0 += s4.x; a1 += s4.y; a2 += s4.z; a3 += s4.w;
    }
    if (qt == 0 && t < 64) {
        float a = 0.f;
        for (int c = 0; c < 16; c++) {
            kspref[(h * 16 + c) * 64 + t] = a;  // exclusive
            a += ksum_ws[(h * 16 + c) * 64 + t];
        }
    }
}

// ---------------------------------------------------------------------------
// Kernel 3: attention output per (c,h). 512 threads / 8 waves. All staging
// via global_load_lds; KV prefix is one DMA of the pre-swizzled scan output.
// grid (16,16).
// ---------------------------------------------------------------------------
__global__ __launch_bounds__(512, 2)
void attn_out2(const u16* __restrict__ qkb, const u16* __restrict__ vT_b,
               const u16* __restrict__ kvpref_b, const float* __restrict__ kspref,
               u16* __restrict__ attnb)
{
    __shared__ __align__(16) u16 smem[29824];  // 59648 B
    u16* q_l   = smem;           // [128][64] swizzled (8192)
    u16* k_l   = smem + 8192;    // [128][64] swizzled (8192)
    u16* kvT_l = smem + 16384;   // [64][64] swizzled (4096)
    u16* vT_l  = smem + 20480;   // [64][128] swizzled (8192)
    u16* P_l   = smem;           // [128][136] (17408) — aliases q+k+kv when dead
    float* kpref  = (float*)(smem + 28672);  // [64]
    float* denom4 = kpref + 64;              // [4][128]

    const int c = blockIdx.x, h = blockIdx.y;
    const int t = threadIdx.x;
    const int lane = t & 63, w = t >> 6;
    const int ln = lane & 15, q4 = lane >> 4;

    // --- async staging: q,k rows (swizzled), vT rows (swizzled), kv prefix ---
    {
        const int row = t >> 3, cc = t & 7;
        const size_t gq = (size_t)(c * CHUNK + row) * 2048 + h * 64
                        + (size_t)((cc ^ (row & 7)) << 3);
        gl_lds16(qkb + gq,        &q_l[t * 8]);
        gl_lds16(qkb + gq + 1024, &k_l[t * 8]);
        const int row2 = row + 64;
        const size_t gq2 = (size_t)(c * CHUNK + row2) * 2048 + h * 64
                         + (size_t)((cc ^ (row2 & 7)) << 3);
        gl_lds16(qkb + gq2,        &q_l[4096 + t * 8]);
        gl_lds16(qkb + gq2 + 1024, &k_l[4096 + t * 8]);
        const int d = t >> 4, cv = t & 15;
        gl_lds16(vT_b + (size_t)(h * 64 + d) * 2048 + c * 128 + ((cv ^ (d & 7)) << 3),
                 &vT_l[t * 8]);
        const int d2 = d + 32;
        gl_lds16(vT_b + (size_t)(h * 64 + d2) * 2048 + c * 128 + ((cv ^ (d2 & 7)) << 3),
                 &vT_l[4096 + t * 8]);
        gl_lds16(kvpref_b + (((size_t)(h * 16 + c)) << 12) + t * 8, &kvT_l[t * 8]);
    }
    if (t < 64) kpref[t] = kspref[(h * 16 + c) * 64 + t];
    __syncthreads();

    // --- P = QK^T : wave tile 64 rows x 32 cols, K=64 ---
    const int pm = (w >> 2) * 64, pn = (w & 3) * 32;
    floatx4 pacc[4][2];
#pragma unroll
    for (int i = 0; i < 4; i++)
#pragma unroll
        for (int j = 0; j < 2; j++) pacc[i][j] = (floatx4)0.0f;
#pragma unroll
    for (int s = 0; s < 2; s++) {
        const int rc = (((s * 4 + q4) ^ (ln & 7)) << 3);
        short8 af[4], bfr[2];
#pragma unroll
        for (int i = 0; i < 4; i++)
            af[i] = *(const short8*)&q_l[(pm + i * 16 + ln) * 64 + rc];
#pragma unroll
        for (int j = 0; j < 2; j++)
            bfr[j] = *(const short8*)&k_l[(pn + j * 16 + ln) * 64 + rc];
#pragma unroll
        for (int i = 0; i < 4; i++)
#pragma unroll
            for (int j = 0; j < 2; j++)
                pacc[i][j] = __builtin_amdgcn_mfma_f32_16x16x32_bf16(af[i], bfr[j], pacc[i][j], 0, 0, 0);
    }
    // --- causal mask + partial rowsum (per 32-col group) ---
#pragma unroll
    for (int i = 0; i < 4; i++)
#pragma unroll
        for (int r = 0; r < 4; r++) {
            int rowi = pm + i * 16 + q4 * 4 + r;
            float rs = 0.f;
#pragma unroll
            for (int j = 0; j < 2; j++) {
                int col = pn + j * 16 + ln;
                float p = pacc[i][j][r];
                if (col > rowi) p = 0.f;
                pacc[i][j][r] = p;
                rs += p;
            }
#pragma unroll
            for (int off = 1; off < 16; off <<= 1) rs += __shfl_xor(rs, off, 64);
            if (ln == 0) denom4[(w & 3) * 128 + rowi] = rs;
        }
    // --- O_inter = Q @ KV_prefix : wave rows ob..ob+15 ---
    const int ob = w * 16;
    floatx4 oacc[4];
#pragma unroll
    for (int j = 0; j < 4; j++) oacc[j] = (floatx4)0.0f;
#pragma unroll
    for (int s = 0; s < 2; s++) {
        const int rc = (((s * 4 + q4) ^ (ln & 7)) << 3);
        short8 af = *(const short8*)&q_l[(ob + ln) * 64 + rc];
#pragma unroll
        for (int j = 0; j < 4; j++) {
            short8 bfr = *(const short8*)&kvT_l[(j * 16 + ln) * 64 + rc];
            oacc[j] = __builtin_amdgcn_mfma_f32_16x16x32_bf16(af, bfr, oacc[j], 0, 0, 0);
        }
    }
    __syncthreads();  // denom rowsums visible; q/k/kv MFMA reads done
    // --- denominator inter: q_i . kpref ---
    if (t < 128) {
        float s = 0.f;
#pragma unroll
        for (int c8 = 0; c8 < 8; c8++) {
            ushortx8 v8 = *(const ushortx8*)&q_l[t * 64 + ((c8 ^ (t & 7)) << 3)];
#pragma unroll
            for (int jj = 0; jj < 8; jj++) s += bf2f(v8[jj]) * kpref[c8 * 8 + jj];
        }
        denom4[t] += s;
    }
    __syncthreads();  // q_l reads done; safe to overwrite with P
    // --- write masked P (bf16, unswizzled, pad 136) ---
#pragma unroll
    for (int i = 0; i < 4; i++)
#pragma unroll
        for (int j = 0; j < 2; j++)
#pragma unroll
            for (int r = 0; r < 4; r++) {
                int rowi = pm + i * 16 + q4 * 4 + r;
                int col = pn + j * 16 + ln;
                P_l[rowi * 136 + col] = f2bf(pacc[i][j][r]);
            }
    __syncthreads();
    // --- O_intra = P @ V : rows ob..ob+15, causal skip ---
    for (int ks = 0; ks <= (w >> 1); ks++) {
        short8 af = *(const short8*)&P_l[(ob + ln) * 136 + ks * 32 + q4 * 8];
        const int rc = (((ks * 4 + q4) ^ (ln & 7)) << 3);
#pragma unroll
        for (int j = 0; j < 4; j++) {
            short8 bfr = *(const short8*)&vT_l[(j * 16 + ln) * 128 + rc];
            oacc[j] = __builtin_amdgcn_mfma_f32_16x16x32_bf16(af, bfr, oacc[j], 0, 0, 0);
        }
    }
    // --- normalize + store ---
#pragma unroll
    for (int r = 0; r < 4; r++) {
        const int rowi = ob + q4 * 4 + r;
        float den = denom4[rowi] + denom4[128 + rowi] + denom4[256 + rowi] + denom4[384 + rowi];
        den = fmaxf(den, 1e-6f);
#pragma unroll
        for (int j = 0; j < 4; j++) {
            int e = j * 16 + ln;
            attnb[(size_t)(c * CHUNK + rowi) * HIDDEN + h * HD + e] = f2bf(oacc[j][r] / den);
        }
    }
}

// ---------------------------------------------------------------------------
// Kernel 4: out = attn @ Wo^T, 64x64 tile (512 blocks = 2/CU), fp32 out.
// ---------------------------------------------------------------------------
__global__ __launch_bounds__(256, 3)
void out_gemm64(const u16* __restrict__ A, const u16* __restrict__ Bm,
                float* __restrict__ out)
{
    __shared__ u16 As[64 * 64];
    __shared__ u16 Bs[64 * 64];
    const int n0 = blockIdx.x * 64, m0 = blockIdx.y * 64;
    const int t = threadIdx.x;
    const int lane = t & 63, wave = t >> 6;
    const int ln = lane & 15, q4 = lane >> 4;
    const int wm = (wave >> 1) * 32, wn = (wave & 1) * 32;
    const int r_in = t >> 3;
    const int csw = (((t & 7) ^ (r_in & 7)) << 3);

    const u16* Ag = A + (size_t)(m0 + r_in) * 1024 + csw;
    const u16* Bg = Bm + (size_t)(n0 + r_in) * 1024 + csw;

    floatx4 acc[2][2];
#pragma unroll
    for (int i = 0; i < 2; i++)
#pragma unroll
        for (int j = 0; j < 2; j++) acc[i][j] = (floatx4)0.0f;

    for (int k0 = 0; k0 < 1024; k0 += 64) {
        if (k0) __syncthreads();
        gl_lds16(Ag, &As[t * 8]);
        gl_lds16(Ag + 32 * 1024, &As[2048 + t * 8]);
        gl_lds16(Bg, &Bs[t * 8]);
        gl_lds16(Bg + 32 * 1024, &Bs[2048 + t * 8]);
        Ag += 64; Bg += 64;
        __syncthreads();
#pragma unroll
        for (int s = 0; s < 2; s++) {
            const int rc = (((s * 4 + q4) ^ (ln & 7)) << 3);
            short8 af[2], bfr[2];
#pragma unroll
            for (int i = 0; i < 2; i++)
                af[i] = *(const short8*)&As[(wm + i * 16 + ln) * 64 + rc];
#pragma unroll
            for (int j = 0; j < 2; j++)
                bfr[j] = *(const short8*)&Bs[(wn + j * 16 + ln) * 64 + rc];
#pragma unroll
            for (int i = 0; i < 2; i++)
#pragma unroll
                for (int j = 0; j < 2; j++)
                    acc[i][j] = __builtin_amdgcn_mfma_f32_16x16x32_bf16(af[i], bfr[j], acc[i][j], 0, 0, 0);
        }
    }
#pragma unroll
    for (int i = 0; i < 2; i++)
#pragma unroll
        for (int j = 0; j < 2; j++)
#pragma unroll
            for (int r = 0; r < 4; r++) {
                int m = m0 + wm + i * 16 + q4 * 4 + r;
                int n = n0 + wn + j * 16 + ln;
                out[(size_t)m * 1024 + n] = acc[i][j][r];
            }
}

// ---------------------------------------------------------------------------
// Workspace layout (40 MB used, no aliasing):
//   xb     @  0 MB   4 MB   Wb @ 4 MB 6 MB   Wob @ 10 MB 2 MB
//   qkb    @ 12 MB   8 MB   kT_b @ 20 MB 4 MB   vT_b @ 24 MB 4 MB
//   S_ws   @ 28 MB   4 MB   ksum @ 32 MB 256 KB  attnb @ 33 MB 4 MB
//   kvpref @ 37 MB   2 MB   kspref @ 39 MB 64 KB
// ---------------------------------------------------------------------------
extern "C" void kernel_launch(void* const* d_in, const int* in_sizes, int n_in,
                              void* d_out, int out_size, void* d_ws, size_t ws_size,
                              hipStream_t stream)
{
    const float* x  = (const float*)d_in[0];
    const float* Wq = (const float*)d_in[1];
    const float* Wk = (const float*)d_in[2];
    const float* Wv = (const float*)d_in[3];
    const float* Wo = (const float*)d_in[4];
    float* out = (float*)d_out;

    char* ws = (char*)d_ws;
    const size_t MB = 1024 * 1024;
    u16* xb    = (u16*)(ws);
    u16* Wb    = (u16*)(ws + 4 * MB);
    u16* Wob   = (u16*)(ws + 10 * MB);
    u16* qkb   = (u16*)(ws + 12 * MB);
    u16* kT_b  = (u16*)(ws + 20 * MB);
    u16* vT_b  = (u16*)(ws + 24 * MB);
    float* S_ws    = (float*)(ws + 28 * MB);
    float* ksum_ws = (float*)(ws + 32 * MB);
    u16* attnb = (u16*)(ws + 33 * MB);
    u16* kvpref_b = (u16*)(ws + 37 * MB);
    float* kspref = (float*)(ws + 39 * MB);

    convert_all<<<2048, 256, 0, stream>>>(x, Wq, Wk, Wv, Wo, xb, Wb, Wob);
    qkv_gemm128<<<dim3(24, 16), 256, 0, stream>>>(xb, Wb, qkb, kT_b, vT_b);
    chunk_stats2<<<dim3(NCHUNK, NH), 256, 0, stream>>>(kT_b, vT_b, S_ws, ksum_ws);
    scan_kv<<<dim3(NH, 4), 256, 0, stream>>>(S_ws, ksum_ws, kvpref_b, kspref);
    attn_out2<<<dim3(NCHUNK, NH), 512, 0, stream>>>(qkb, vT_b, kvpref_b, kspref, attnb);
    out_gemm64<<<dim3(16, 32), 256, 0, stream>>>(attnb, Wob, out);
}

// Round 4
// 128.467 us; speedup vs baseline: 5.5794x; 1.0077x over previous
//
#include <hip/hip_runtime.h>
#include <hip/hip_bf16.h>

typedef __attribute__((ext_vector_type(8))) short short8;
typedef __attribute__((ext_vector_type(4))) float floatx4;
typedef __attribute__((ext_vector_type(8))) unsigned short ushortx8;
typedef __attribute__((ext_vector_type(4))) unsigned short ushortx4;
typedef unsigned short u16;

#define HIDDEN 1024
#define NH 16
#define HD 64
#define SEQ 2048
#define CHUNK 128
#define NCHUNK (SEQ / CHUNK)  // 16

__device__ __forceinline__ u16 f2bf(float f) {
    union { float f; unsigned u; } v; v.f = f;
    unsigned r = v.u + 0x7fffu + ((v.u >> 16) & 1u);
    return (u16)(r >> 16);
}
__device__ __forceinline__ float bf2f(u16 u) {
    union { unsigned u; float f; } v; v.u = ((unsigned)u) << 16;
    return v.f;
}

// async 16B global->LDS. LDS dest is wave-uniform base + lane*16 (no pad);
// read-side bank conflicts handled by XOR chunk swizzle on the GLOBAL addr.
__device__ __forceinline__ void gl_lds16(const u16* g, u16* l) {
    __builtin_amdgcn_global_load_lds(
        (const __attribute__((address_space(1))) void*)g,
        (__attribute__((address_space(3))) void*)l,
        16, 0, 0);
}

// ---------------------------------------------------------------------------
// Kernel 0: fp32 -> bf16 of x, Wq|Wk|Wv (fused rows), Wo. ~36 MB traffic.
// ---------------------------------------------------------------------------
__global__ __launch_bounds__(256)
void convert_all(const float* __restrict__ x,  const float* __restrict__ Wq,
                 const float* __restrict__ Wk, const float* __restrict__ Wv,
                 const float* __restrict__ Wo,
                 u16* __restrict__ xb, u16* __restrict__ Wb, u16* __restrict__ Wob)
{
    const int total4 = 1572864;  // 6M floats / 4
    for (int idx = blockIdx.x * 256 + threadIdx.x; idx < total4; idx += gridDim.x * 256) {
        const float4* src; u16* dst; int off;
        if (idx < 524288)       { src = (const float4*)x;  dst = xb;            off = idx; }
        else if (idx < 786432)  { src = (const float4*)Wq; dst = Wb;            off = idx - 524288; }
        else if (idx < 1048576) { src = (const float4*)Wk; dst = Wb + 1048576;  off = idx - 786432; }
        else if (idx < 1310720) { src = (const float4*)Wv; dst = Wb + 2097152;  off = idx - 1048576; }
        else                    { src = (const float4*)Wo; dst = Wob;           off = idx - 1310720; }
        float4 v = src[off];
        ushortx4 u = { f2bf(v.x), f2bf(v.y), f2bf(v.z), f2bf(v.w) };
        *(ushortx4*)(dst + (size_t)off * 4) = u;
    }
}

// ---------------------------------------------------------------------------
// Kernel 1: fused QKV GEMM, 64x128 tile (768 blocks = 3/CU exactly), BK=64,
// NOW 2-phase double-buffered (T3-minimum): issue next K-tile's
// global_load_lds into buf^1 BEFORE computing buf; one barrier per K-step.
// Accumulation order per output unchanged -> bit-identical results.
// Epilogue identical to round-1.
// ---------------------------------------------------------------------------
__global__ __launch_bounds__(256, 3)
void qkv_gemm64(const u16* __restrict__ A, const u16* __restrict__ Bm,
                u16* __restrict__ qkb, u16* __restrict__ kT_b, u16* __restrict__ vT_b)
{
    __shared__ u16 As[2][64 * 64];    // 2 x 8 KB
    __shared__ u16 Bs[2][128 * 64];   // 2 x 16 KB  (total 48 KB, 3/CU = 144)
    const int n0 = blockIdx.x * 128, m0 = blockIdx.y * 64;
    const int t = threadIdx.x;
    const int lane = t & 63, wave = t >> 6;
    const int ln = lane & 15, q4 = lane >> 4;
    const int wm = (wave >> 1) * 32, wn = (wave & 1) * 64;
    const int r_in = t >> 3;
    const int csw = (((t & 7) ^ (r_in & 7)) << 3);

    const u16* Ag = A + (size_t)(m0 + r_in) * 1024 + csw;
    const u16* Bg = Bm + (size_t)(n0 + r_in) * 1024 + csw;

    floatx4 acc[2][4];
#pragma unroll
    for (int i = 0; i < 2; i++)
#pragma unroll
        for (int j = 0; j < 4; j++) acc[i][j] = (floatx4)0.0f;

    auto stage = [&](u16* Asb, u16* Bsb, int k0) {
        gl_lds16(Ag + k0, &Asb[t * 8]);
        gl_lds16(Ag + k0 + 32 * 1024, &Asb[2048 + t * 8]);
#pragma unroll
        for (int i = 0; i < 4; i++)
            gl_lds16(Bg + k0 + (size_t)i * 32 * 1024, &Bsb[i * 2048 + t * 8]);
    };
    auto compute = [&](const u16* Asb, const u16* Bsb) {
#pragma unroll
        for (int s = 0; s < 2; s++) {
            const int rc = (((s * 4 + q4) ^ (ln & 7)) << 3);
            short8 af[2], bfr[4];
#pragma unroll
            for (int i = 0; i < 2; i++)
                af[i] = *(const short8*)&Asb[(wm + i * 16 + ln) * 64 + rc];
#pragma unroll
            for (int j = 0; j < 4; j++)
                bfr[j] = *(const short8*)&Bsb[(wn + j * 16 + ln) * 64 + rc];
#pragma unroll
            for (int i = 0; i < 2; i++)
#pragma unroll
                for (int j = 0; j < 4; j++)
                    acc[i][j] = __builtin_amdgcn_mfma_f32_16x16x32_bf16(af[i], bfr[j], acc[i][j], 0, 0, 0);
        }
    };

    stage(As[0], Bs[0], 0);
    __syncthreads();            // vmcnt(0) drain + barrier (compiler-emitted)
    int cur = 0;
    for (int k0 = 64; k0 < 1024; k0 += 64) {
        stage(As[cur ^ 1], Bs[cur ^ 1], k0);   // prefetch next, in flight
        compute(As[cur], Bs[cur]);             // MFMAs cover DMA latency
        __syncthreads();                       // drain + barrier, once/K-step
        cur ^= 1;
    }
    compute(As[cur], Bs[cur]);

    const int grp = n0 >> 10;  // 0=q 1=k 2=v (block-uniform)
#pragma unroll
    for (int i = 0; i < 2; i++)
#pragma unroll
        for (int j = 0; j < 4; j++) {
            const int mb = m0 + wm + i * 16 + q4 * 4;
            const int n = n0 + wn + j * 16 + ln;
            const int nh = n & 1023, h = nh >> 6, e = nh & 63;
            float vals[4];
#pragma unroll
            for (int r = 0; r < 4; r++) {
                float v = acc[i][j][r];
                if (grp < 2) v = (v > 0.f) ? (v + 1.f) : __expf(v);
                vals[r] = v;
            }
            if (grp == 0) {
#pragma unroll
                for (int r = 0; r < 4; r++) qkb[(size_t)(mb + r) * 2048 + nh] = f2bf(vals[r]);
            } else if (grp == 1) {
#pragma unroll
                for (int r = 0; r < 4; r++) qkb[(size_t)(mb + r) * 2048 + 1024 + nh] = f2bf(vals[r]);
                ushortx4 u = { f2bf(vals[0]), f2bf(vals[1]), f2bf(vals[2]), f2bf(vals[3]) };
                *(ushortx4*)&kT_b[(size_t)(h * 64 + e) * 2048 + mb] = u;
            } else {
                ushortx4 u = { f2bf(vals[0]), f2bf(vals[1]), f2bf(vals[2]), f2bf(vals[3]) };
                *(ushortx4*)&vT_b[(size_t)(h * 64 + e) * 2048 + mb] = u;
            }
        }
}

// ---------------------------------------------------------------------------
// Kernel 2: S_c[d][e] = sum_l K[l][d] V[l][e] per (c,h) via MFMA, staged
// entirely with global_load_lds from kT_b/vT_b (reduction axis l contig).
// Stores S^T [e][d] + ksum[d]. grid (16,16).
// ---------------------------------------------------------------------------
__global__ __launch_bounds__(256, 2)
void chunk_stats2(const u16* __restrict__ kT_b, const u16* __restrict__ vT_b,
                  float* __restrict__ S_ws, float* __restrict__ ksum_ws)
{
    __shared__ u16 kT_l[64 * 128];
    __shared__ u16 vT_l[64 * 128];
    const int c = blockIdx.x, h = blockIdx.y;
    const int t = threadIdx.x;
    const int lane = t & 63, w = t >> 6;
    const int ln = lane & 15, q4 = lane >> 4;
#pragma unroll
    for (int i = 0; i < 4; i++) {
        const int d0 = w * 16 + i * 4 + (lane >> 4);
        const int cc = lane & 15;
        const size_t gsrc = (size_t)(h * 64 + d0) * 2048 + c * 128 + ((cc ^ (d0 & 7)) << 3);
        gl_lds16(kT_b + gsrc, &kT_l[(w * 16 + i * 4) * 128 + lane * 8]);
        gl_lds16(vT_b + gsrc, &vT_l[(w * 16 + i * 4) * 128 + lane * 8]);
    }
    __syncthreads();
    floatx4 sacc[4];
#pragma unroll
    for (int j = 0; j < 4; j++) sacc[j] = (floatx4)0.0f;
#pragma unroll
    for (int ks = 0; ks < 4; ks++) {
        const int rc = (((ks * 4 + q4) ^ (ln & 7)) << 3);
        short8 af = *(const short8*)&kT_l[(w * 16 + ln) * 128 + rc];
#pragma unroll
        for (int j = 0; j < 4; j++) {
            short8 bfr = *(const short8*)&vT_l[(j * 16 + ln) * 128 + rc];
            sacc[j] = __builtin_amdgcn_mfma_f32_16x16x32_bf16(af, bfr, sacc[j], 0, 0, 0);
        }
    }
    float* Sp = S_ws + ((size_t)(h * NCHUNK + c) << 12);
#pragma unroll
    for (int j = 0; j < 4; j++)
#pragma unroll
        for (int r = 0; r < 4; r++) {
            int d = w * 16 + q4 * 4 + r;
            int e = j * 16 + ln;
            Sp[e * 64 + d] = sacc[j][r];  // S^T [e][d]
        }
    if (t < 64) {  // ksum[d]: row-sum of kT_l (swizzle permutes within row; sum invariant)
        float s = 0.f;
#pragma unroll
        for (int cc = 0; cc < 16; cc++) {
            ushortx8 v8 = *(const ushortx8*)&kT_l[t * 128 + cc * 8];
#pragma unroll
            for (int jj = 0; jj < 8; jj++) s += bf2f(v8[jj]);
        }
        ksum_ws[(h * NCHUNK + c) * 64 + t] = s;
    }
}

// ---------------------------------------------------------------------------
// Kernel 2b: exclusive chunk-prefix scan of S (fp32 accumulate) -> kvpref_b
// bf16 PRE-SWIZZLED, + exclusive ksum prefix. grid (NH, 4).
// ---------------------------------------------------------------------------
__global__ __launch_bounds__(256)
void scan_kv(const float* __restrict__ S_ws, const float* __restrict__ ksum_ws,
             u16* __restrict__ kvpref_b, float* __restrict__ kspref)
{
    const int h = blockIdx.x, qt = blockIdx.y;
    const int t = threadIdx.x;
    const int li = qt * 1024 + t * 4;          // linear elem in S^T [e][d]
    const int e = li >> 6, d0 = li & 63;       // 4 consecutive d's, one row
    const int slot = e * 64 + ((((d0 >> 3) ^ (e & 7)) << 3) | (d0 & 7));
    float a0 = 0.f, a1 = 0.f, a2 = 0.f, a3 = 0.f;
    for (int c = 0; c < 16; c++) {
        ushortx4 u = { f2bf(a0), f2bf(a1), f2bf(a2), f2bf(a3) };  // exclusive
        *(ushortx4*)&kvpref_b[(((size_t)(h * 16 + c)) << 12) + slot] = u;
        float4 s4 = *(const float4*)(S_ws + (((size_t)(h * 16 + c)) << 12) + li);
        a0 += s4.x; a1 += s4.y; a2 += s4.z; a3 += s4.w;
    }
    if (qt == 0 && t < 64) {
        float a = 0.f;
        for (int c = 0; c < 16; c++) {
            kspref[(h * 16 + c) * 64 + t] = a;  // exclusive
            a += ksum_ws[(h * 16 + c) * 64 + t];
        }
    }
}

// ---------------------------------------------------------------------------
// Kernel 3: attention output per (c,h). 512 threads / 8 waves. All staging
// via global_load_lds; KV prefix is one DMA of the pre-swizzled scan output.
// grid (16,16).
// ---------------------------------------------------------------------------
__global__ __launch_bounds__(512, 2)
void attn_out2(const u16* __restrict__ qkb, const u16* __restrict__ vT_b,
               const u16* __restrict__ kvpref_b, const float* __restrict__ kspref,
               u16* __restrict__ attnb)
{
    __shared__ __align__(16) u16 smem[29824];  // 59648 B
    u16* q_l   = smem;           // [128][64] swizzled (8192)
    u16* k_l   = smem + 8192;    // [128][64] swizzled (8192)
    u16* kvT_l = smem + 16384;   // [64][64] swizzled (4096)
    u16* vT_l  = smem + 20480;   // [64][128] swizzled (8192)
    u16* P_l   = smem;           // [128][136] (17408) — aliases q+k+kv when dead
    float* kpref  = (float*)(smem + 28672);  // [64]
    float* denom4 = kpref + 64;              // [4][128]

    const int c = blockIdx.x, h = blockIdx.y;
    const int t = threadIdx.x;
    const int lane = t & 63, w = t >> 6;
    const int ln = lane & 15, q4 = lane >> 4;

    // --- async staging: q,k rows (swizzled), vT rows (swizzled), kv prefix ---
    {
        const int row = t >> 3, cc = t & 7;
        const size_t gq = (size_t)(c * CHUNK + row) * 2048 + h * 64
                        + (size_t)((cc ^ (row & 7)) << 3);
        gl_lds16(qkb + gq,        &q_l[t * 8]);
        gl_lds16(qkb + gq + 1024, &k_l[t * 8]);
        const int row2 = row + 64;
        const size_t gq2 = (size_t)(c * CHUNK + row2) * 2048 + h * 64
                         + (size_t)((cc ^ (row2 & 7)) << 3);
        gl_lds16(qkb + gq2,        &q_l[4096 + t * 8]);
        gl_lds16(qkb + gq2 + 1024, &k_l[4096 + t * 8]);
        const int d = t >> 4, cv = t & 15;
        gl_lds16(vT_b + (size_t)(h * 64 + d) * 2048 + c * 128 + ((cv ^ (d & 7)) << 3),
                 &vT_l[t * 8]);
        const int d2 = d + 32;
        gl_lds16(vT_b + (size_t)(h * 64 + d2) * 2048 + c * 128 + ((cv ^ (d2 & 7)) << 3),
                 &vT_l[4096 + t * 8]);
        gl_lds16(kvpref_b + (((size_t)(h * 16 + c)) << 12) + t * 8, &kvT_l[t * 8]);
    }
    if (t < 64) kpref[t] = kspref[(h * 16 + c) * 64 + t];
    __syncthreads();

    // --- P = QK^T : wave tile 64 rows x 32 cols, K=64 ---
    const int pm = (w >> 2) * 64, pn = (w & 3) * 32;
    floatx4 pacc[4][2];
#pragma unroll
    for (int i = 0; i < 4; i++)
#pragma unroll
        for (int j = 0; j < 2; j++) pacc[i][j] = (floatx4)0.0f;
#pragma unroll
    for (int s = 0; s < 2; s++) {
        const int rc = (((s * 4 + q4) ^ (ln & 7)) << 3);
        short8 af[4], bfr[2];
#pragma unroll
        for (int i = 0; i < 4; i++)
            af[i] = *(const short8*)&q_l[(pm + i * 16 + ln) * 64 + rc];
#pragma unroll
        for (int j = 0; j < 2; j++)
            bfr[j] = *(const short8*)&k_l[(pn + j * 16 + ln) * 64 + rc];
#pragma unroll
        for (int i = 0; i < 4; i++)
#pragma unroll
            for (int j = 0; j < 2; j++)
                pacc[i][j] = __builtin_amdgcn_mfma_f32_16x16x32_bf16(af[i], bfr[j], pacc[i][j], 0, 0, 0);
    }
    // --- causal mask + partial rowsum (per 32-col group) ---
#pragma unroll
    for (int i = 0; i < 4; i++)
#pragma unroll
        for (int r = 0; r < 4; r++) {
            int rowi = pm + i * 16 + q4 * 4 + r;
            float rs = 0.f;
#pragma unroll
            for (int j = 0; j < 2; j++) {
                int col = pn + j * 16 + ln;
                float p = pacc[i][j][r];
                if (col > rowi) p = 0.f;
                pacc[i][j][r] = p;
                rs += p;
            }
#pragma unroll
            for (int off = 1; off < 16; off <<= 1) rs += __shfl_xor(rs, off, 64);
            if (ln == 0) denom4[(w & 3) * 128 + rowi] = rs;
        }
    // --- O_inter = Q @ KV_prefix : wave rows ob..ob+15 ---
    const int ob = w * 16;
    floatx4 oacc[4];
#pragma unroll
    for (int j = 0; j < 4; j++) oacc[j] = (floatx4)0.0f;
#pragma unroll
    for (int s = 0; s < 2; s++) {
        const int rc = (((s * 4 + q4) ^ (ln & 7)) << 3);
        short8 af = *(const short8*)&q_l[(ob + ln) * 64 + rc];
#pragma unroll
        for (int j = 0; j < 4; j++) {
            short8 bfr = *(const short8*)&kvT_l[(j * 16 + ln) * 64 + rc];
            oacc[j] = __builtin_amdgcn_mfma_f32_16x16x32_bf16(af, bfr, oacc[j], 0, 0, 0);
        }
    }
    __syncthreads();  // denom rowsums visible; q/k/kv MFMA reads done
    // --- denominator inter: q_i . kpref ---
    if (t < 128) {
        float s = 0.f;
#pragma unroll
        for (int c8 = 0; c8 < 8; c8++) {
            ushortx8 v8 = *(const ushortx8*)&q_l[t * 64 + ((c8 ^ (t & 7)) << 3)];
#pragma unroll
            for (int jj = 0; jj < 8; jj++) s += bf2f(v8[jj]) * kpref[c8 * 8 + jj];
        }
        denom4[t] += s;
    }
    __syncthreads();  // q_l reads done; safe to overwrite with P
    // --- write masked P (bf16, unswizzled, pad 136) ---
#pragma unroll
    for (int i = 0; i < 4; i++)
#pragma unroll
        for (int j = 0; j < 2; j++)
#pragma unroll
            for (int r = 0; r < 4; r++) {
                int rowi = pm + i * 16 + q4 * 4 + r;
                int col = pn + j * 16 + ln;
                P_l[rowi * 136 + col] = f2bf(pacc[i][j][r]);
            }
    __syncthreads();
    // --- O_intra = P @ V : rows ob..ob+15, causal skip ---
    for (int ks = 0; ks <= (w >> 1); ks++) {
        short8 af = *(const short8*)&P_l[(ob + ln) * 136 + ks * 32 + q4 * 8];
        const int rc = (((ks * 4 + q4) ^ (ln & 7)) << 3);
#pragma unroll
        for (int j = 0; j < 4; j++) {
            short8 bfr = *(const short8*)&vT_l[(j * 16 + ln) * 128 + rc];
            oacc[j] = __builtin_amdgcn_mfma_f32_16x16x32_bf16(af, bfr, oacc[j], 0, 0, 0);
        }
    }
    // --- normalize + store ---
#pragma unroll
    for (int r = 0; r < 4; r++) {
        const int rowi = ob + q4 * 4 + r;
        float den = denom4[rowi] + denom4[128 + rowi] + denom4[256 + rowi] + denom4[384 + rowi];
        den = fmaxf(den, 1e-6f);
#pragma unroll
        for (int j = 0; j < 4; j++) {
            int e = j * 16 + ln;
            attnb[(size_t)(c * CHUNK + rowi) * HIDDEN + h * HD + e] = f2bf(oacc[j][r] / den);
        }
    }
}

// ---------------------------------------------------------------------------
// Kernel 4: out = attn @ Wo^T, 64x64 tile (512 blocks = 2/CU), fp32 out.
// NOW 2-phase double-buffered like qkv (32 KB LDS, 3/CU possible).
// ---------------------------------------------------------------------------
__global__ __launch_bounds__(256, 3)
void out_gemm64(const u16* __restrict__ A, const u16* __restrict__ Bm,
                float* __restrict__ out)
{
    __shared__ u16 As[2][64 * 64];
    __shared__ u16 Bs[2][64 * 64];
    const int n0 = blockIdx.x * 64, m0 = blockIdx.y * 64;
    const int t = threadIdx.x;
    const int lane = t & 63, wave = t >> 6;
    const int ln = lane & 15, q4 = lane >> 4;
    const int wm = (wave >> 1) * 32, wn = (wave & 1) * 32;
    const int r_in = t >> 3;
    const int csw = (((t & 7) ^ (r_in & 7)) << 3);

    const u16* Ag = A + (size_t)(m0 + r_in) * 1024 + csw;
    const u16* Bg = Bm + (size_t)(n0 + r_in) * 1024 + csw;

    floatx4 acc[2][2];
#pragma unroll
    for (int i = 0; i < 2; i++)
#pragma unroll
        for (int j = 0; j < 2; j++) acc[i][j] = (floatx4)0.0f;

    auto stage = [&](u16* Asb, u16* Bsb, int k0) {
        gl_lds16(Ag + k0, &Asb[t * 8]);
        gl_lds16(Ag + k0 + 32 * 1024, &Asb[2048 + t * 8]);
        gl_lds16(Bg + k0, &Bsb[t * 8]);
        gl_lds16(Bg + k0 + 32 * 1024, &Bsb[2048 + t * 8]);
    };
    auto compute = [&](const u16* Asb, const u16* Bsb) {
#pragma unroll
        for (int s = 0; s < 2; s++) {
            const int rc = (((s * 4 + q4) ^ (ln & 7)) << 3);
            short8 af[2], bfr[2];
#pragma unroll
            for (int i = 0; i < 2; i++)
                af[i] = *(const short8*)&Asb[(wm + i * 16 + ln) * 64 + rc];
#pragma unroll
            for (int j = 0; j < 2; j++)
                bfr[j] = *(const short8*)&Bsb[(wn + j * 16 + ln) * 64 + rc];
#pragma unroll
            for (int i = 0; i < 2; i++)
#pragma unroll
                for (int j = 0; j < 2; j++)
                    acc[i][j] = __builtin_amdgcn_mfma_f32_16x16x32_bf16(af[i], bfr[j], acc[i][j], 0, 0, 0);
        }
    };

    stage(As[0], Bs[0], 0);
    __syncthreads();
    int cur = 0;
    for (int k0 = 64; k0 < 1024; k0 += 64) {
        stage(As[cur ^ 1], Bs[cur ^ 1], k0);
        compute(As[cur], Bs[cur]);
        __syncthreads();
        cur ^= 1;
    }
    compute(As[cur], Bs[cur]);

#pragma unroll
    for (int i = 0; i < 2; i++)
#pragma unroll
        for (int j = 0; j < 2; j++)
#pragma unroll
            for (int r = 0; r < 4; r++) {
                int m = m0 + wm + i * 16 + q4 * 4 + r;
                int n = n0 + wn + j * 16 + ln;
                out[(size_t)m * 1024 + n] = acc[i][j][r];
            }
}

// ---------------------------------------------------------------------------
// Workspace layout (40 MB used, no aliasing):
//   xb     @  0 MB   4 MB   Wb @ 4 MB 6 MB   Wob @ 10 MB 2 MB
//   qkb    @ 12 MB   8 MB   kT_b @ 20 MB 4 MB   vT_b @ 24 MB 4 MB
//   S_ws   @ 28 MB   4 MB   ksum @ 32 MB 256 KB  attnb @ 33 MB 4 MB
//   kvpref @ 37 MB   2 MB   kspref @ 39 MB 64 KB
// ---------------------------------------------------------------------------
extern "C" void kernel_launch(void* const* d_in, const int* in_sizes, int n_in,
                              void* d_out, int out_size, void* d_ws, size_t ws_size,
                              hipStream_t stream)
{
    const float* x  = (const float*)d_in[0];
    const float* Wq = (const float*)d_in[1];
    const float* Wk = (const float*)d_in[2];
    const float* Wv = (const float*)d_in[3];
    const float* Wo = (const float*)d_in[4];
    float* out = (float*)d_out;

    char* ws = (char*)d_ws;
    const size_t MB = 1024 * 1024;
    u16* xb    = (u16*)(ws);
    u16* Wb    = (u16*)(ws + 4 * MB);
    u16* Wob   = (u16*)(ws + 10 * MB);
    u16* qkb   = (u16*)(ws + 12 * MB);
    u16* kT_b  = (u16*)(ws + 20 * MB);
    u16* vT_b  = (u16*)(ws + 24 * MB);
    float* S_ws    = (float*)(ws + 28 * MB);
    float* ksum_ws = (float*)(ws + 32 * MB);
    u16* attnb = (u16*)(ws + 33 * MB);
    u16* kvpref_b = (u16*)(ws + 37 * MB);
    float* kspref = (float*)(ws + 39 * MB);

    convert_all<<<2048, 256, 0, stream>>>(x, Wq, Wk, Wv, Wo, xb, Wb, Wob);
    qkv_gemm64<<<dim3(24, 32), 256, 0, stream>>>(xb, Wb, qkb, kT_b, vT_b);
    chunk_stats2<<<dim3(NCHUNK, NH), 256, 0, stream>>>(kT_b, vT_b, S_ws, ksum_ws);
    scan_kv<<<dim3(NH, 4), 256, 0, stream>>>(S_ws, ksum_ws, kvpref_b, kspref);
    attn_out2<<<dim3(NCHUNK, NH), 512, 0, stream>>>(qkb, vT_b, kvpref_b, kspref, attnb);
    out_gemm64<<<dim3(16, 32), 256, 0, stream>>>(attnb, Wob, out);
}

// Round 5
// 123.584 us; speedup vs baseline: 5.7998x; 1.0395x over previous
//
#include <hip/hip_runtime.h>
#include <hip/hip_bf16.h>

typedef __attribute__((ext_vector_type(8))) short short8;
typedef __attribute__((ext_vector_type(4))) float floatx4;
typedef __attribute__((ext_vector_type(8))) unsigned short ushortx8;
typedef __attribute__((ext_vector_type(4))) unsigned short ushortx4;
typedef unsigned short u16;

#define HIDDEN 1024
#define NH 16
#define HD 64
#define SEQ 2048
#define CHUNK 128
#define NCHUNK (SEQ / CHUNK)  // 16

__device__ __forceinline__ u16 f2bf(float f) {
    union { float f; unsigned u; } v; v.f = f;
    unsigned r = v.u + 0x7fffu + ((v.u >> 16) & 1u);
    return (u16)(r >> 16);
}
__device__ __forceinline__ float bf2f(u16 u) {
    union { unsigned u; float f; } v; v.u = ((unsigned)u) << 16;
    return v.f;
}

// async 16B global->LDS. LDS dest is wave-uniform base + lane*16 (no pad);
// read-side bank conflicts handled by XOR chunk swizzle on the GLOBAL addr.
__device__ __forceinline__ void gl_lds16(const u16* g, u16* l) {
    __builtin_amdgcn_global_load_lds(
        (const __attribute__((address_space(1))) void*)g,
        (__attribute__((address_space(3))) void*)l,
        16, 0, 0);
}

// ---------------------------------------------------------------------------
// Kernel 0: fp32 -> bf16 of x, Wq|Wk|Wv (fused rows), Wo. ~36 MB traffic.
// ---------------------------------------------------------------------------
__global__ __launch_bounds__(256)
void convert_all(const float* __restrict__ x,  const float* __restrict__ Wq,
                 const float* __restrict__ Wk, const float* __restrict__ Wv,
                 const float* __restrict__ Wo,
                 u16* __restrict__ xb, u16* __restrict__ Wb, u16* __restrict__ Wob)
{
    const int total4 = 1572864;  // 6M floats / 4
    for (int idx = blockIdx.x * 256 + threadIdx.x; idx < total4; idx += gridDim.x * 256) {
        const float4* src; u16* dst; int off;
        if (idx < 524288)       { src = (const float4*)x;  dst = xb;            off = idx; }
        else if (idx < 786432)  { src = (const float4*)Wq; dst = Wb;            off = idx - 524288; }
        else if (idx < 1048576) { src = (const float4*)Wk; dst = Wb + 1048576;  off = idx - 786432; }
        else if (idx < 1310720) { src = (const float4*)Wv; dst = Wb + 2097152;  off = idx - 1048576; }
        else                    { src = (const float4*)Wo; dst = Wob;           off = idx - 1310720; }
        float4 v = src[off];
        ushortx4 u = { f2bf(v.x), f2bf(v.y), f2bf(v.z), f2bf(v.w) };
        *(ushortx4*)(dst + (size_t)off * 4) = u;
    }
}

// ---------------------------------------------------------------------------
// Kernel 1: fused QKV GEMM, 64x128 tile (768 blocks = 3/CU), BK=64.
// T4 counted-vmcnt pipeline (m218): stage tiles k,k+1 up front; per K-step
// wait vmcnt(6) (= the tile staged TWO steps ago; the newest 6 loads stay in
// flight across both barriers), compute, barrier, restage freed buffer.
// Accumulation order per output unchanged -> bit-identical results.
// ---------------------------------------------------------------------------
__global__ __launch_bounds__(256, 3)
void qkv_gemm64(const u16* __restrict__ A, const u16* __restrict__ Bm,
                u16* __restrict__ qkb, u16* __restrict__ kT_b, u16* __restrict__ vT_b)
{
    __shared__ u16 As[2][64 * 64];    // 2 x 8 KB
    __shared__ u16 Bs[2][128 * 64];   // 2 x 16 KB (48 KB total, 3/CU = 144)
    const int n0 = blockIdx.x * 128, m0 = blockIdx.y * 64;
    const int t = threadIdx.x;
    const int lane = t & 63, wave = t >> 6;
    const int ln = lane & 15, q4 = lane >> 4;
    const int wm = (wave >> 1) * 32, wn = (wave & 1) * 64;
    const int r_in = t >> 3;
    const int csw = (((t & 7) ^ (r_in & 7)) << 3);

    const u16* Ag = A + (size_t)(m0 + r_in) * 1024 + csw;
    const u16* Bg = Bm + (size_t)(n0 + r_in) * 1024 + csw;

    floatx4 acc[2][4];
#pragma unroll
    for (int i = 0; i < 2; i++)
#pragma unroll
        for (int j = 0; j < 4; j++) acc[i][j] = (floatx4)0.0f;

    auto stage = [&](int buf, int k) {
        const int k0 = k * 64;
        gl_lds16(Ag + k0, &As[buf][t * 8]);
        gl_lds16(Ag + k0 + 32 * 1024, &As[buf][2048 + t * 8]);
#pragma unroll
        for (int i = 0; i < 4; i++)
            gl_lds16(Bg + k0 + (size_t)i * 32 * 1024, &Bs[buf][i * 2048 + t * 8]);
    };
    auto compute = [&](int buf) {
#pragma unroll
        for (int s = 0; s < 2; s++) {
            const int rc = (((s * 4 + q4) ^ (ln & 7)) << 3);
            short8 af[2], bfr[4];
#pragma unroll
            for (int i = 0; i < 2; i++)
                af[i] = *(const short8*)&As[buf][(wm + i * 16 + ln) * 64 + rc];
#pragma unroll
            for (int j = 0; j < 4; j++)
                bfr[j] = *(const short8*)&Bs[buf][(wn + j * 16 + ln) * 64 + rc];
#pragma unroll
            for (int i = 0; i < 2; i++)
#pragma unroll
                for (int j = 0; j < 4; j++)
                    acc[i][j] = __builtin_amdgcn_mfma_f32_16x16x32_bf16(af[i], bfr[j], acc[i][j], 0, 0, 0);
        }
    };

    stage(0, 0);
    stage(1, 1);
    for (int i = 0; i < 14; i++) {
        asm volatile("s_waitcnt vmcnt(6)" ::: "memory");   // tile i landed (i+1 in flight)
        __builtin_amdgcn_sched_barrier(0);
        __builtin_amdgcn_s_barrier();                      // all waves' DMA landed
        compute(i & 1);
        __builtin_amdgcn_sched_barrier(0);
        __builtin_amdgcn_s_barrier();                      // all waves done reading buf
        stage(i & 1, i + 2);                               // overwrite freed buffer
    }
    asm volatile("s_waitcnt vmcnt(6)" ::: "memory");
    __builtin_amdgcn_sched_barrier(0);
    __builtin_amdgcn_s_barrier();
    compute(0);                                            // K-step 14
    asm volatile("s_waitcnt vmcnt(0)" ::: "memory");
    __builtin_amdgcn_sched_barrier(0);
    __builtin_amdgcn_s_barrier();
    compute(1);                                            // K-step 15

    const int grp = n0 >> 10;  // 0=q 1=k 2=v (block-uniform)
#pragma unroll
    for (int i = 0; i < 2; i++)
#pragma unroll
        for (int j = 0; j < 4; j++) {
            const int mb = m0 + wm + i * 16 + q4 * 4;
            const int n = n0 + wn + j * 16 + ln;
            const int nh = n & 1023, h = nh >> 6, e = nh & 63;
            float vals[4];
#pragma unroll
            for (int r = 0; r < 4; r++) {
                float v = acc[i][j][r];
                if (grp < 2) v = (v > 0.f) ? (v + 1.f) : __expf(v);
                vals[r] = v;
            }
            if (grp == 0) {
#pragma unroll
                for (int r = 0; r < 4; r++) qkb[(size_t)(mb + r) * 2048 + nh] = f2bf(vals[r]);
            } else if (grp == 1) {
#pragma unroll
                for (int r = 0; r < 4; r++) qkb[(size_t)(mb + r) * 2048 + 1024 + nh] = f2bf(vals[r]);
                ushortx4 u = { f2bf(vals[0]), f2bf(vals[1]), f2bf(vals[2]), f2bf(vals[3]) };
                *(ushortx4*)&kT_b[(size_t)(h * 64 + e) * 2048 + mb] = u;
            } else {
                ushortx4 u = { f2bf(vals[0]), f2bf(vals[1]), f2bf(vals[2]), f2bf(vals[3]) };
                *(ushortx4*)&vT_b[(size_t)(h * 64 + e) * 2048 + mb] = u;
            }
        }
}

// ---------------------------------------------------------------------------
// Kernel 2: S_c[d][e] = sum_l K[l][d] V[l][e] per (c,h) via MFMA, staged
// entirely with global_load_lds from kT_b/vT_b (reduction axis l contig).
// Stores S^T [e][d] + ksum[d]. grid (16,16).
// ---------------------------------------------------------------------------
__global__ __launch_bounds__(256, 2)
void chunk_stats2(const u16* __restrict__ kT_b, const u16* __restrict__ vT_b,
                  float* __restrict__ S_ws, float* __restrict__ ksum_ws)
{
    __shared__ u16 kT_l[64 * 128];
    __shared__ u16 vT_l[64 * 128];
    const int c = blockIdx.x, h = blockIdx.y;
    const int t = threadIdx.x;
    const int lane = t & 63, w = t >> 6;
    const int ln = lane & 15, q4 = lane >> 4;
#pragma unroll
    for (int i = 0; i < 4; i++) {
        const int d0 = w * 16 + i * 4 + (lane >> 4);
        const int cc = lane & 15;
        const size_t gsrc = (size_t)(h * 64 + d0) * 2048 + c * 128 + ((cc ^ (d0 & 7)) << 3);
        gl_lds16(kT_b + gsrc, &kT_l[(w * 16 + i * 4) * 128 + lane * 8]);
        gl_lds16(vT_b + gsrc, &vT_l[(w * 16 + i * 4) * 128 + lane * 8]);
    }
    __syncthreads();
    floatx4 sacc[4];
#pragma unroll
    for (int j = 0; j < 4; j++) sacc[j] = (floatx4)0.0f;
#pragma unroll
    for (int ks = 0; ks < 4; ks++) {
        const int rc = (((ks * 4 + q4) ^ (ln & 7)) << 3);
        short8 af = *(const short8*)&kT_l[(w * 16 + ln) * 128 + rc];
#pragma unroll
        for (int j = 0; j < 4; j++) {
            short8 bfr = *(const short8*)&vT_l[(j * 16 + ln) * 128 + rc];
            sacc[j] = __builtin_amdgcn_mfma_f32_16x16x32_bf16(af, bfr, sacc[j], 0, 0, 0);
        }
    }
    float* Sp = S_ws + ((size_t)(h * NCHUNK + c) << 12);
#pragma unroll
    for (int j = 0; j < 4; j++)
#pragma unroll
        for (int r = 0; r < 4; r++) {
            int d = w * 16 + q4 * 4 + r;
            int e = j * 16 + ln;
            Sp[e * 64 + d] = sacc[j][r];  // S^T [e][d]
        }
    if (t < 64) {  // ksum[d]: row-sum of kT_l (swizzle permutes within row; sum invariant)
        float s = 0.f;
#pragma unroll
        for (int cc = 0; cc < 16; cc++) {
            ushortx8 v8 = *(const ushortx8*)&kT_l[t * 128 + cc * 8];
#pragma unroll
            for (int jj = 0; jj < 8; jj++) s += bf2f(v8[jj]);
        }
        ksum_ws[(h * NCHUNK + c) * 64 + t] = s;
    }
}

// ---------------------------------------------------------------------------
// Kernel 2b: exclusive chunk-prefix scan of S (fp32 accumulate) -> kvpref_b
// bf16 PRE-SWIZZLED, + exclusive ksum prefix. grid (NH, 4).
// ---------------------------------------------------------------------------
__global__ __launch_bounds__(256)
void scan_kv(const float* __restrict__ S_ws, const float* __restrict__ ksum_ws,
             u16* __restrict__ kvpref_b, float* __restrict__ kspref)
{
    const int h = blockIdx.x, qt = blockIdx.y;
    const int t = threadIdx.x;
    const int li = qt * 1024 + t * 4;          // linear elem in S^T [e][d]
    const int e = li >> 6, d0 = li & 63;       // 4 consecutive d's, one row
    const int slot = e * 64 + ((((d0 >> 3) ^ (e & 7)) << 3) | (d0 & 7));
    float a0 = 0.f, a1 = 0.f, a2 = 0.f, a3 = 0.f;
    for (int c = 0; c < 16; c++) {
        ushortx4 u = { f2bf(a0), f2bf(a1), f2bf(a2), f2bf(a3) };  // exclusive
        *(ushortx4*)&kvpref_b[(((size_t)(h * 16 + c)) << 12) + slot] = u;
        float4 s4 = *(const float4*)(S_ws + (((size_t)(h * 16 + c)) << 12) + li);
        a0 += s4.x; a1 += s4.y; a2 += s4.z; a3 += s4.w;
    }
    if (qt == 0 && t < 64) {
        float a = 0.f;
        for (int c = 0; c < 16; c++) {
            kspref[(h * 16 + c) * 64 + t] = a;  // exclusive
            a += ksum_ws[(h * 16 + c) * 64 + t];
        }
    }
}

// ---------------------------------------------------------------------------
// Kernel 3: attention output per (c,h). 512 threads / 8 waves. All staging
// via global_load_lds; KV prefix is one DMA of the pre-swizzled scan output.
// grid (16,16).
// ---------------------------------------------------------------------------
__global__ __launch_bounds__(512, 2)
void attn_out2(const u16* __restrict__ qkb, const u16* __restrict__ vT_b,
               const u16* __restrict__ kvpref_b, const float* __restrict__ kspref,
               u16* __restrict__ attnb)
{
    __shared__ __align__(16) u16 smem[29824];  // 59648 B
    u16* q_l   = smem;           // [128][64] swizzled (8192)
    u16* k_l   = smem + 8192;    // [128][64] swizzled (8192)
    u16* kvT_l = smem + 16384;   // [64][64] swizzled (4096)
    u16* vT_l  = smem + 20480;   // [64][128] swizzled (8192)
    u16* P_l   = smem;           // [128][136] (17408) — aliases q+k+kv when dead
    float* kpref  = (float*)(smem + 28672);  // [64]
    float* denom4 = kpref + 64;              // [4][128]

    const int c = blockIdx.x, h = blockIdx.y;
    const int t = threadIdx.x;
    const int lane = t & 63, w = t >> 6;
    const int ln = lane & 15, q4 = lane >> 4;

    // --- async staging: q,k rows (swizzled), vT rows (swizzled), kv prefix ---
    {
        const int row = t >> 3, cc = t & 7;
        const size_t gq = (size_t)(c * CHUNK + row) * 2048 + h * 64
                        + (size_t)((cc ^ (row & 7)) << 3);
        gl_lds16(qkb + gq,        &q_l[t * 8]);
        gl_lds16(qkb + gq + 1024, &k_l[t * 8]);
        const int row2 = row + 64;
        const size_t gq2 = (size_t)(c * CHUNK + row2) * 2048 + h * 64
                         + (size_t)((cc ^ (row2 & 7)) << 3);
        gl_lds16(qkb + gq2,        &q_l[4096 + t * 8]);
        gl_lds16(qkb + gq2 + 1024, &k_l[4096 + t * 8]);
        const int d = t >> 4, cv = t & 15;
        gl_lds16(vT_b + (size_t)(h * 64 + d) * 2048 + c * 128 + ((cv ^ (d & 7)) << 3),
                 &vT_l[t * 8]);
        const int d2 = d + 32;
        gl_lds16(vT_b + (size_t)(h * 64 + d2) * 2048 + c * 128 + ((cv ^ (d2 & 7)) << 3),
                 &vT_l[4096 + t * 8]);
        gl_lds16(kvpref_b + (((size_t)(h * 16 + c)) << 12) + t * 8, &kvT_l[t * 8]);
    }
    if (t < 64) kpref[t] = kspref[(h * 16 + c) * 64 + t];
    __syncthreads();

    // --- P = QK^T : wave tile 64 rows x 32 cols, K=64 ---
    const int pm = (w >> 2) * 64, pn = (w & 3) * 32;
    floatx4 pacc[4][2];
#pragma unroll
    for (int i = 0; i < 4; i++)
#pragma unroll
        for (int j = 0; j < 2; j++) pacc[i][j] = (floatx4)0.0f;
#pragma unroll
    for (int s = 0; s < 2; s++) {
        const int rc = (((s * 4 + q4) ^ (ln & 7)) << 3);
        short8 af[4], bfr[2];
#pragma unroll
        for (int i = 0; i < 4; i++)
            af[i] = *(const short8*)&q_l[(pm + i * 16 + ln) * 64 + rc];
#pragma unroll
        for (int j = 0; j < 2; j++)
            bfr[j] = *(const short8*)&k_l[(pn + j * 16 + ln) * 64 + rc];
#pragma unroll
        for (int i = 0; i < 4; i++)
#pragma unroll
            for (int j = 0; j < 2; j++)
                pacc[i][j] = __builtin_amdgcn_mfma_f32_16x16x32_bf16(af[i], bfr[j], pacc[i][j], 0, 0, 0);
    }
    // --- causal mask + partial rowsum (per 32-col group) ---
#pragma unroll
    for (int i = 0; i < 4; i++)
#pragma unroll
        for (int r = 0; r < 4; r++) {
            int rowi = pm + i * 16 + q4 * 4 + r;
            float rs = 0.f;
#pragma unroll
            for (int j = 0; j < 2; j++) {
                int col = pn + j * 16 + ln;
                float p = pacc[i][j][r];
                if (col > rowi) p = 0.f;
                pacc[i][j][r] = p;
                rs += p;
            }
#pragma unroll
            for (int off = 1; off < 16; off <<= 1) rs += __shfl_xor(rs, off, 64);
            if (ln == 0) denom4[(w & 3) * 128 + rowi] = rs;
        }
    // --- O_inter = Q @ KV_prefix : wave rows ob..ob+15 ---
    const int ob = w * 16;
    floatx4 oacc[4];
#pragma unroll
    for (int j = 0; j < 4; j++) oacc[j] = (floatx4)0.0f;
#pragma unroll
    for (int s = 0; s < 2; s++) {
        const int rc = (((s * 4 + q4) ^ (ln & 7)) << 3);
        short8 af = *(const short8*)&q_l[(ob + ln) * 64 + rc];
#pragma unroll
        for (int j = 0; j < 4; j++) {
            short8 bfr = *(const short8*)&kvT_l[(j * 16 + ln) * 64 + rc];
            oacc[j] = __builtin_amdgcn_mfma_f32_16x16x32_bf16(af, bfr, oacc[j], 0, 0, 0);
        }
    }
    __syncthreads();  // denom rowsums visible; q/k/kv MFMA reads done
    // --- denominator inter: q_i . kpref ---
    if (t < 128) {
        float s = 0.f;
#pragma unroll
        for (int c8 = 0; c8 < 8; c8++) {
            ushortx8 v8 = *(const ushortx8*)&q_l[t * 64 + ((c8 ^ (t & 7)) << 3)];
#pragma unroll
            for (int jj = 0; jj < 8; jj++) s += bf2f(v8[jj]) * kpref[c8 * 8 + jj];
        }
        denom4[t] += s;
    }
    __syncthreads();  // q_l reads done; safe to overwrite with P
    // --- write masked P (bf16, unswizzled, pad 136) ---
#pragma unroll
    for (int i = 0; i < 4; i++)
#pragma unroll
        for (int j = 0; j < 2; j++)
#pragma unroll
            for (int r = 0; r < 4; r++) {
                int rowi = pm + i * 16 + q4 * 4 + r;
                int col = pn + j * 16 + ln;
                P_l[rowi * 136 + col] = f2bf(pacc[i][j][r]);
            }
    __syncthreads();
    // --- O_intra = P @ V : rows ob..ob+15, causal skip ---
    for (int ks = 0; ks <= (w >> 1); ks++) {
        short8 af = *(const short8*)&P_l[(ob + ln) * 136 + ks * 32 + q4 * 8];
        const int rc = (((ks * 4 + q4) ^ (ln & 7)) << 3);
#pragma unroll
        for (int j = 0; j < 4; j++) {
            short8 bfr = *(const short8*)&vT_l[(j * 16 + ln) * 128 + rc];
            oacc[j] = __builtin_amdgcn_mfma_f32_16x16x32_bf16(af, bfr, oacc[j], 0, 0, 0);
        }
    }
    // --- normalize + store ---
#pragma unroll
    for (int r = 0; r < 4; r++) {
        const int rowi = ob + q4 * 4 + r;
        float den = denom4[rowi] + denom4[128 + rowi] + denom4[256 + rowi] + denom4[384 + rowi];
        den = fmaxf(den, 1e-6f);
#pragma unroll
        for (int j = 0; j < 4; j++) {
            int e = j * 16 + ln;
            attnb[(size_t)(c * CHUNK + rowi) * HIDDEN + h * HD + e] = f2bf(oacc[j][r] / den);
        }
    }
}

// ---------------------------------------------------------------------------
// Kernel 4: out = attn @ Wo^T, 64x64 tile (512 blocks = 2/CU), fp32 out.
// Same T4 counted-vmcnt pipeline (4 loads/stage -> vmcnt(4)).
// ---------------------------------------------------------------------------
__global__ __launch_bounds__(256, 3)
void out_gemm64(const u16* __restrict__ A, const u16* __restrict__ Bm,
                float* __restrict__ out)
{
    __shared__ u16 As[2][64 * 64];
    __shared__ u16 Bs[2][64 * 64];
    const int n0 = blockIdx.x * 64, m0 = blockIdx.y * 64;
    const int t = threadIdx.x;
    const int lane = t & 63, wave = t >> 6;
    const int ln = lane & 15, q4 = lane >> 4;
    const int wm = (wave >> 1) * 32, wn = (wave & 1) * 32;
    const int r_in = t >> 3;
    const int csw = (((t & 7) ^ (r_in & 7)) << 3);

    const u16* Ag = A + (size_t)(m0 + r_in) * 1024 + csw;
    const u16* Bg = Bm + (size_t)(n0 + r_in) * 1024 + csw;

    floatx4 acc[2][2];
#pragma unroll
    for (int i = 0; i < 2; i++)
#pragma unroll
        for (int j = 0; j < 2; j++) acc[i][j] = (floatx4)0.0f;

    auto stage = [&](int buf, int k) {
        const int k0 = k * 64;
        gl_lds16(Ag + k0, &As[buf][t * 8]);
        gl_lds16(Ag + k0 + 32 * 1024, &As[buf][2048 + t * 8]);
        gl_lds16(Bg + k0, &Bs[buf][t * 8]);
        gl_lds16(Bg + k0 + 32 * 1024, &Bs[buf][2048 + t * 8]);
    };
    auto compute = [&](int buf) {
#pragma unroll
        for (int s = 0; s < 2; s++) {
            const int rc = (((s * 4 + q4) ^ (ln & 7)) << 3);
            short8 af[2], bfr[2];
#pragma unroll
            for (int i = 0; i < 2; i++)
                af[i] = *(const short8*)&As[buf][(wm + i * 16 + ln) * 64 + rc];
#pragma unroll
            for (int j = 0; j < 2; j++)
                bfr[j] = *(const short8*)&Bs[buf][(wn + j * 16 + ln) * 64 + rc];
#pragma unroll
            for (int i = 0; i < 2; i++)
#pragma unroll
                for (int j = 0; j < 2; j++)
                    acc[i][j] = __builtin_amdgcn_mfma_f32_16x16x32_bf16(af[i], bfr[j], acc[i][j], 0, 0, 0);
        }
    };

    stage(0, 0);
    stage(1, 1);
    for (int i = 0; i < 14; i++) {
        asm volatile("s_waitcnt vmcnt(4)" ::: "memory");
        __builtin_amdgcn_sched_barrier(0);
        __builtin_amdgcn_s_barrier();
        compute(i & 1);
        __builtin_amdgcn_sched_barrier(0);
        __builtin_amdgcn_s_barrier();
        stage(i & 1, i + 2);
    }
    asm volatile("s_waitcnt vmcnt(4)" ::: "memory");
    __builtin_amdgcn_sched_barrier(0);
    __builtin_amdgcn_s_barrier();
    compute(0);
    asm volatile("s_waitcnt vmcnt(0)" ::: "memory");
    __builtin_amdgcn_sched_barrier(0);
    __builtin_amdgcn_s_barrier();
    compute(1);

#pragma unroll
    for (int i = 0; i < 2; i++)
#pragma unroll
        for (int j = 0; j < 2; j++)
#pragma unroll
            for (int r = 0; r < 4; r++) {
                int m = m0 + wm + i * 16 + q4 * 4 + r;
                int n = n0 + wn + j * 16 + ln;
                out[(size_t)m * 1024 + n] = acc[i][j][r];
            }
}

// ---------------------------------------------------------------------------
// Workspace layout (40 MB used, no aliasing):
//   xb     @  0 MB   4 MB   Wb @ 4 MB 6 MB   Wob @ 10 MB 2 MB
//   qkb    @ 12 MB   8 MB   kT_b @ 20 MB 4 MB   vT_b @ 24 MB 4 MB
//   S_ws   @ 28 MB   4 MB   ksum @ 32 MB 256 KB  attnb @ 33 MB 4 MB
//   kvpref @ 37 MB   2 MB   kspref @ 39 MB 64 KB
// ---------------------------------------------------------------------------
extern "C" void kernel_launch(void* const* d_in, const int* in_sizes, int n_in,
                              void* d_out, int out_size, void* d_ws, size_t ws_size,
                              hipStream_t stream)
{
    const float* x  = (const float*)d_in[0];
    const float* Wq = (const float*)d_in[1];
    const float* Wk = (const float*)d_in[2];
    const float* Wv = (const float*)d_in[3];
    const float* Wo = (const float*)d_in[4];
    float* out = (float*)d_out;

    char* ws = (char*)d_ws;
    const size_t MB = 1024 * 1024;
    u16* xb    = (u16*)(ws);
    u16* Wb    = (u16*)(ws + 4 * MB);
    u16* Wob   = (u16*)(ws + 10 * MB);
    u16* qkb   = (u16*)(ws + 12 * MB);
    u16* kT_b  = (u16*)(ws + 20 * MB);
    u16* vT_b  = (u16*)(ws + 24 * MB);
    float* S_ws    = (float*)(ws + 28 * MB);
    float* ksum_ws = (float*)(ws + 32 * MB);
    u16* attnb = (u16*)(ws + 33 * MB);
    u16* kvpref_b = (u16*)(ws + 37 * MB);
    float* kspref = (float*)(ws + 39 * MB);

    convert_all<<<2048, 256, 0, stream>>>(x, Wq, Wk, Wv, Wo, xb, Wb, Wob);
    qkv_gemm64<<<dim3(24, 32), 256, 0, stream>>>(xb, Wb, qkb, kT_b, vT_b);
    chunk_stats2<<<dim3(NCHUNK, NH), 256, 0, stream>>>(kT_b, vT_b, S_ws, ksum_ws);
    scan_kv<<<dim3(NH, 4), 256, 0, stream>>>(S_ws, ksum_ws, kvpref_b, kspref);
    attn_out2<<<dim3(NCHUNK, NH), 512, 0, stream>>>(qkb, vT_b, kvpref_b, kspref, attnb);
    out_gemm64<<<dim3(16, 32), 256, 0, stream>>>(attnb, Wob, out);
}